// Round 4
// baseline (621.452 us; speedup 1.0000x reference)
//
#include <hip/hip_runtime.h>
#include <hip/hip_bf16.h>

#define NSPEC 4
#define NFEAT 144
#define RCUT 5.0f
#define RPB 32            // centers (rows) per accum block
#define LDSTRIDE 145      // floats; 145 mod 32 = 17 -> rows skewed across banks

// ---------- utility ----------

__global__ void zero_i32(int* __restrict__ p, int n) {
    int i = blockIdx.x * blockDim.x + threadIdx.x;
    if (i < n) p[i] = 0;
}

__global__ void zero_f32(float* __restrict__ out, int n) {
    int n4 = n >> 2;
    float4* o4 = (float4*)out;
    for (int i = blockIdx.x * blockDim.x + threadIdx.x; i < n4; i += gridDim.x * blockDim.x)
        o4[i] = make_float4(0.f, 0.f, 0.f, 0.f);
    int tail = n & 3;
    if (blockIdx.x == 0 && threadIdx.x < tail) out[n4 * 4 + threadIdx.x] = 0.f;
}

// ---------- stable counting-sort rank of centers by species ----------

__global__ void count_kernel(const int* __restrict__ cs, int n, int* __restrict__ chunkCounts) {
    __shared__ int cnt[NSPEC];
    if (threadIdx.x < NSPEC) cnt[threadIdx.x] = 0;
    __syncthreads();
    int i = blockIdx.x * blockDim.x + threadIdx.x;
    if (i < n) atomicAdd(&cnt[cs[i]], 1);
    __syncthreads();
    if (threadIdx.x < NSPEC) chunkCounts[blockIdx.x * NSPEC + threadIdx.x] = cnt[threadIdx.x];
}

// parallel: 4 waves, wave w scans species w across chunks via shuffle-scan
__global__ void scanP_kernel(const int* __restrict__ chunkCounts, int nChunks,
                             int* __restrict__ chunkOffsets) {
    __shared__ int totals[NSPEC];
    __shared__ int base4[NSPEC];
    int w = threadIdx.x >> 6;     // species
    int lane = threadIdx.x & 63;
    int carry = 0;
    for (int base = 0; base < nChunks; base += 64) {
        int c = base + lane;
        int v = (c < nChunks) ? chunkCounts[c * NSPEC + w] : 0;
        int incl = v;
        #pragma unroll
        for (int off = 1; off < 64; off <<= 1) {
            int t = __shfl_up(incl, off);
            if (lane >= off) incl += t;
        }
        if (c < nChunks) chunkOffsets[c * NSPEC + w] = carry + incl - v;
        carry += __shfl(incl, 63);
    }
    if (lane == 0) totals[w] = carry;
    __syncthreads();
    if (threadIdx.x == 0) {
        int b = 0;
        for (int s = 0; s < NSPEC; ++s) { base4[s] = b; b += totals[s]; }
    }
    __syncthreads();
    for (int i = threadIdx.x; i < nChunks * NSPEC; i += blockDim.x)
        chunkOffsets[i] += base4[i & (NSPEC - 1)];
}

__global__ void dest_kernel(const int* __restrict__ cs, int n,
                            const int* __restrict__ chunkOffsets, int* __restrict__ dest) {
    __shared__ int waveCnt[4][NSPEC];
    int chunk = blockIdx.x;
    int i = chunk * blockDim.x + threadIdx.x;
    int s = (i < n) ? cs[i] : -1;
    int lane = threadIdx.x & 63;
    int wave = threadIdx.x >> 6;

    int lanePrefix = 0;
    for (int sp = 0; sp < NSPEC; ++sp) {
        unsigned long long b = __ballot(s == sp);
        if (lane == 0) waveCnt[wave][sp] = __popcll(b);
        if (sp == s) lanePrefix = __popcll(b & ((1ull << lane) - 1ull));
    }
    __syncthreads();
    if (i < n) {
        int wp = 0;
        for (int w = 0; w < wave; ++w) wp += waveCnt[w][s];
        dest[i] = chunkOffsets[chunk * NSPEC + s] + wp + lanePrefix;
    }
}

// ---------- pass 1: histogram over centers + packed payload ----------
// payload u: bits[31:7] = r mantissa/exp (low 7 bits cleared), bits[6:2] = center&31,
// bits[1:0] = species. Culled pairs get sign bit set (r>=0 -> valid u has bit31==0).

__global__ void hist_kernel(const float* __restrict__ dirs, const int* __restrict__ pci,
                            const int* __restrict__ nsi,
                            int* __restrict__ hist, unsigned* __restrict__ uArr, int P) {
    int i = blockIdx.x * blockDim.x + threadIdx.x;
    if (i >= P) return;
    float x = dirs[3 * i + 0], y = dirs[3 * i + 1], z = dirs[3 * i + 2];
    float r2 = x * x + y * y + z * z;
    if (r2 >= RCUT * RCUT) { if (uArr) uArr[i] = 0xFFFFFFFFu; return; }
    int c = pci[i];
    if (uArr) {
        float r = sqrtf(r2);
        uArr[i] = (__float_as_uint(r) & 0xFFFFFF80u) | ((unsigned)(c & (RPB - 1)) << 2) |
                  (unsigned)nsi[i];
    }
    atomicAdd(&hist[c], 1);
}

// ---------- hierarchical exclusive scan over NC bins ----------

__global__ void scanA(const int* __restrict__ hist, int n, int* __restrict__ blockTot) {
    __shared__ int sdata[256];
    int base = blockIdx.x * 1024;
    int t = threadIdx.x;
    int i0 = base + t * 4;
    int v0 = (i0 + 0 < n) ? hist[i0 + 0] : 0;
    int v1 = (i0 + 1 < n) ? hist[i0 + 1] : 0;
    int v2 = (i0 + 2 < n) ? hist[i0 + 2] : 0;
    int v3 = (i0 + 3 < n) ? hist[i0 + 3] : 0;
    sdata[t] = v0 + v1 + v2 + v3;
    __syncthreads();
    for (int off = 1; off < 256; off <<= 1) {
        int x = (t >= off) ? sdata[t - off] : 0;
        __syncthreads();
        sdata[t] += x;
        __syncthreads();
    }
    if (t == 255) blockTot[blockIdx.x] = sdata[255];
}

__global__ void scanB(int* __restrict__ blockTot, int nb) {
    int lane = threadIdx.x;  // 64 threads
    int carry = 0;
    for (int base = 0; base < nb; base += 64) {
        int i = base + lane;
        int v = (i < nb) ? blockTot[i] : 0;
        int incl = v;
        #pragma unroll
        for (int off = 1; off < 64; off <<= 1) {
            int t = __shfl_up(incl, off);
            if (lane >= off) incl += t;
        }
        if (i < nb) blockTot[i] = carry + incl - v;
        carry += __shfl(incl, 63);
    }
}

__global__ void scanC(int* __restrict__ hist, int n, const int* __restrict__ blockBase) {
    __shared__ int sdata[256];
    int base = blockIdx.x * 1024;
    int t = threadIdx.x;
    int i0 = base + t * 4;
    int v0 = (i0 + 0 < n) ? hist[i0 + 0] : 0;
    int v1 = (i0 + 1 < n) ? hist[i0 + 1] : 0;
    int v2 = (i0 + 2 < n) ? hist[i0 + 2] : 0;
    int v3 = (i0 + 3 < n) ? hist[i0 + 3] : 0;
    sdata[t] = v0 + v1 + v2 + v3;
    __syncthreads();
    for (int off = 1; off < 256; off <<= 1) {
        int x = (t >= off) ? sdata[t - off] : 0;
        __syncthreads();
        sdata[t] += x;
        __syncthreads();
    }
    int ebase = blockBase[blockIdx.x] + ((t > 0) ? sdata[t - 1] : 0);
    if (i0 + 0 < n) hist[i0 + 0] = ebase;
    if (i0 + 1 < n) hist[i0 + 1] = ebase + v0;
    if (i0 + 2 < n) hist[i0 + 2] = ebase + v0 + v1;
    if (i0 + 3 < n) hist[i0 + 3] = ebase + v0 + v1 + v2;
}

// ---------- scatter pairs into center-sorted order ----------

__global__ void scatter_fast(const unsigned* __restrict__ uArr, const int* __restrict__ pci,
                             int* __restrict__ offsets, unsigned* __restrict__ sorted, int P) {
    int i = blockIdx.x * blockDim.x + threadIdx.x;
    if (i >= P) return;
    unsigned u = uArr[i];
    if ((int)u < 0) return;  // culled
    int pos = atomicAdd(&offsets[pci[i]], 1);
    sorted[pos] = u;
}

__global__ void scatter_slow(const float* __restrict__ dirs, const int* __restrict__ pci,
                             const int* __restrict__ nsi,
                             int* __restrict__ offsets, unsigned* __restrict__ sorted, int P) {
    int i = blockIdx.x * blockDim.x + threadIdx.x;
    if (i >= P) return;
    float x = dirs[3 * i + 0], y = dirs[3 * i + 1], z = dirs[3 * i + 2];
    float r2 = x * x + y * y + z * z;
    if (r2 >= RCUT * RCUT) return;
    float r = sqrtf(r2);
    int c = pci[i];
    int pos = atomicAdd(&offsets[c], 1);
    sorted[pos] = (__float_as_uint(r) & 0xFFFFFF80u) | ((unsigned)(c & (RPB - 1)) << 2) |
                  (unsigned)nsi[i];
}

// ---------- accumulate: block owns RPB centers, lanes own pairs, LDS atomics ----------

__global__ void __launch_bounds__(256) accum_kernel(
        const int* __restrict__ offs /* end-of-bin per center */,
        const unsigned* __restrict__ sorted,
        const int* __restrict__ dest,
        float* __restrict__ out, int NC) {
    __shared__ float smem[RPB * LDSTRIDE];
    __shared__ int destLds[RPB];

    int tid = threadIdx.x;
    int rowBase = blockIdx.x * RPB;

    for (int i = tid; i < RPB * LDSTRIDE; i += 256) smem[i] = 0.f;
    if (tid < RPB && rowBase + tid < NC) destLds[tid] = dest[rowBase + tid];
    __syncthreads();

    int lastRow = min(rowBase + RPB, NC) - 1;
    int pairStart = (rowBase == 0) ? 0 : offs[rowBase - 1];
    int pairEnd = offs[lastRow];

    for (int p = pairStart + tid; p < pairEnd; p += 256) {
        unsigned u = sorted[p];
        float r = __uint_as_float(u & 0xFFFFFF80u);
        int s = (int)(u & 3u);
        int lr = (int)((u >> 2) & (RPB - 1));
        float r2 = r * r;
        float fc = 0.5f * (__cosf(0.6283185307179586f * r) + 1.0f);  // pi/RCUT
        float q = __expf(-r2 * (1.0f / (RCUT * RCUT)));
        float* row = smem + lr * LDSTRIDE + s;
        float rl = fc;
        float e = q;
        #pragma unroll
        for (int n = 0; n < 12; ++n) { atomicAdd(row + n * 4, rl * e); e *= q; }
        rl *= r; e = q;
        #pragma unroll
        for (int n = 0; n < 10; ++n) { atomicAdd(row + 48 + n * 4, rl * e); e *= q; }
        rl *= r; e = q;
        #pragma unroll
        for (int n = 0; n < 8; ++n) { atomicAdd(row + 88 + n * 4, rl * e); e *= q; }
        rl *= r; e = q;
        #pragma unroll
        for (int n = 0; n < 6; ++n) { atomicAdd(row + 120 + n * 4, rl * e); e *= q; }
    }
    __syncthreads();

    int nRows = min(RPB, NC - rowBase);
    for (int i = tid; i < nRows * NFEAT; i += 256) {
        int j = i / NFEAT;
        int col = i - j * NFEAT;
        out[(size_t)destLds[j] * NFEAT + col] = smem[j * LDSTRIDE + col];
    }
}

// ---------- fallback: direct atomic scatter ----------

__global__ void pair_kernel(const float* __restrict__ dirs,
                            const int* __restrict__ pci,
                            const int* __restrict__ nsi,
                            const int* __restrict__ dest,
                            float* __restrict__ out, int P) {
    int i = blockIdx.x * blockDim.x + threadIdx.x;
    if (i >= P) return;
    float x = dirs[3 * i + 0], y = dirs[3 * i + 1], z = dirs[3 * i + 2];
    float r2 = x * x + y * y + z * z;
    float r = sqrtf(r2);
    if (r >= RCUT) return;
    float fc = 0.5f * (cosf(3.14159265358979323846f * r * (1.0f / RCUT)) + 1.0f);
    float q = expf(-r2 * (1.0f / (RCUT * RCUT)));
    int rowb = dest[pci[i]] * NFEAT;
    int s = nsi[i];
    float* o = out + rowb + s;
    float rl = fc;
    const int nmax[4] = {12, 10, 8, 6};
    const int offl[4] = {0, 48, 88, 120};
    #pragma unroll
    for (int l = 0; l < 4; ++l) {
        float e = q;
        for (int n = 0; n < nmax[l]; ++n) { atomicAdd(o + offl[l] + n * NSPEC, rl * e); e *= q; }
        rl *= r;
    }
}

extern "C" void kernel_launch(void* const* d_in, const int* in_sizes, int n_in,
                              void* d_out, int out_size, void* d_ws, size_t ws_size,
                              hipStream_t stream) {
    const float* dirs = (const float*)d_in[0];
    const int* pci = (const int*)d_in[1];
    const int* nsi = (const int*)d_in[2];
    const int* cs = (const int*)d_in[3];
    int P = in_sizes[1];
    int NC = in_sizes[3];
    float* out = (float*)d_out;

    int nChunks = (NC + 255) / 256;
    int NB = (NC + 1023) / 1024;

    // ws layout (ints)
    int* chunkCounts  = (int*)d_ws;                      // nChunks*4
    int* chunkOffsets = chunkCounts + nChunks * NSPEC;   // nChunks*4
    int* dest         = chunkOffsets + nChunks * NSPEC;  // NC
    int* hist         = dest + NC;                       // NC (becomes end-offsets)
    int* blockTot     = hist + NC;                       // NB
    unsigned* sorted  = (unsigned*)(blockTot + NB);      // P
    unsigned* uArr    = sorted + P;                      // P (optional)

    size_t need_base = ((size_t)(2 * nChunks * NSPEC) + 2 * (size_t)NC + NB + (size_t)P) * sizeof(int);
    size_t need_u    = need_base + (size_t)P * sizeof(int);

    // center -> sorted-row map
    count_kernel<<<nChunks, 256, 0, stream>>>(cs, NC, chunkCounts);
    scanP_kernel<<<1, 256, 0, stream>>>(chunkCounts, nChunks, chunkOffsets);
    dest_kernel<<<nChunks, 256, 0, stream>>>(cs, NC, chunkOffsets, dest);

    if (ws_size >= need_base) {
        bool useU = (ws_size >= need_u);
        zero_i32<<<(NC + 255) / 256, 256, 0, stream>>>(hist, NC);
        hist_kernel<<<(P + 255) / 256, 256, 0, stream>>>(dirs, pci, nsi, hist,
                                                         useU ? uArr : (unsigned*)nullptr, P);
        scanA<<<NB, 256, 0, stream>>>(hist, NC, blockTot);
        scanB<<<1, 64, 0, stream>>>(blockTot, NB);
        scanC<<<NB, 256, 0, stream>>>(hist, NC, blockTot);
        if (useU)
            scatter_fast<<<(P + 255) / 256, 256, 0, stream>>>(uArr, pci, hist, sorted, P);
        else
            scatter_slow<<<(P + 255) / 256, 256, 0, stream>>>(dirs, pci, nsi, hist, sorted, P);
        accum_kernel<<<(NC + RPB - 1) / RPB, 256, 0, stream>>>(hist, sorted, dest, out, NC);
    } else {
        zero_f32<<<2048, 256, 0, stream>>>(out, out_size);
        pair_kernel<<<(P + 255) / 256, 256, 0, stream>>>(dirs, pci, nsi, dest, out, P);
    }
}

// Round 5
// 358.734 us; speedup vs baseline: 1.7323x; 1.7323x over previous
//
#include <hip/hip_runtime.h>
#include <hip/hip_bf16.h>

#define NSPEC 4
#define NFEAT 144
#define RCUT 5.0f
#define RPB 64                 // dest-rows per accum block
#define BPB (RPB * NSPEC)      // key bins per accum block = 256
#define LDSTRIDE 145           // 145 mod 32 = 17 -> rows skewed across banks

// ---------- utility ----------

__global__ void zero_i32(int* __restrict__ p, int n) {
    int i = blockIdx.x * blockDim.x + threadIdx.x;
    if (i < n) p[i] = 0;
}

__global__ void zero_f32(float* __restrict__ out, int n) {
    int n4 = n >> 2;
    float4* o4 = (float4*)out;
    for (int i = blockIdx.x * blockDim.x + threadIdx.x; i < n4; i += gridDim.x * blockDim.x)
        o4[i] = make_float4(0.f, 0.f, 0.f, 0.f);
    int tail = n & 3;
    if (blockIdx.x == 0 && threadIdx.x < tail) out[n4 * 4 + threadIdx.x] = 0.f;
}

// ---------- stable counting-sort rank of centers by species ----------

__global__ void count_kernel(const int* __restrict__ cs, int n, int* __restrict__ chunkCounts) {
    __shared__ int cnt[NSPEC];
    if (threadIdx.x < NSPEC) cnt[threadIdx.x] = 0;
    __syncthreads();
    int i = blockIdx.x * blockDim.x + threadIdx.x;
    if (i < n) atomicAdd(&cnt[cs[i]], 1);
    __syncthreads();
    if (threadIdx.x < NSPEC) chunkCounts[blockIdx.x * NSPEC + threadIdx.x] = cnt[threadIdx.x];
}

__global__ void scanP_kernel(const int* __restrict__ chunkCounts, int nChunks,
                             int* __restrict__ chunkOffsets) {
    __shared__ int totals[NSPEC];
    __shared__ int base4[NSPEC];
    int w = threadIdx.x >> 6;     // species
    int lane = threadIdx.x & 63;
    int carry = 0;
    for (int base = 0; base < nChunks; base += 64) {
        int c = base + lane;
        int v = (c < nChunks) ? chunkCounts[c * NSPEC + w] : 0;
        int incl = v;
        #pragma unroll
        for (int off = 1; off < 64; off <<= 1) {
            int t = __shfl_up(incl, off);
            if (lane >= off) incl += t;
        }
        if (c < nChunks) chunkOffsets[c * NSPEC + w] = carry + incl - v;
        carry += __shfl(incl, 63);
    }
    if (lane == 0) totals[w] = carry;
    __syncthreads();
    if (threadIdx.x == 0) {
        int b = 0;
        for (int s = 0; s < NSPEC; ++s) { base4[s] = b; b += totals[s]; }
    }
    __syncthreads();
    for (int i = threadIdx.x; i < nChunks * NSPEC; i += blockDim.x)
        chunkOffsets[i] += base4[i & (NSPEC - 1)];
}

__global__ void dest_kernel(const int* __restrict__ cs, int n,
                            const int* __restrict__ chunkOffsets, int* __restrict__ dest) {
    __shared__ int waveCnt[4][NSPEC];
    int chunk = blockIdx.x;
    int i = chunk * blockDim.x + threadIdx.x;
    int s = (i < n) ? cs[i] : -1;
    int lane = threadIdx.x & 63;
    int wave = threadIdx.x >> 6;

    int lanePrefix = 0;
    for (int sp = 0; sp < NSPEC; ++sp) {
        unsigned long long b = __ballot(s == sp);
        if (lane == 0) waveCnt[wave][sp] = __popcll(b);
        if (sp == s) lanePrefix = __popcll(b & ((1ull << lane) - 1ull));
    }
    __syncthreads();
    if (i < n) {
        int wp = 0;
        for (int w = 0; w < wave; ++w) wp += waveCnt[w][s];
        dest[i] = chunkOffsets[chunk * NSPEC + s] + wp + lanePrefix;
    }
}

// ---------- pass 1: histogram over 4*NC key bins (key = destRow*4 + species) ----------

__global__ void hist_kernel(const float* __restrict__ dirs, const int* __restrict__ pci,
                            const int* __restrict__ nsi, const int* __restrict__ dest,
                            int* __restrict__ hist, int P) {
    int i = blockIdx.x * blockDim.x + threadIdx.x;
    if (i >= P) return;
    float x = dirs[3 * i + 0], y = dirs[3 * i + 1], z = dirs[3 * i + 2];
    float r2 = x * x + y * y + z * z;
    if (r2 >= RCUT * RCUT) return;
    int key = dest[pci[i]] * NSPEC + nsi[i];
    atomicAdd(&hist[key], 1);
}

// ---------- hierarchical exclusive scan over NK bins ----------

__global__ void scanA(const int* __restrict__ hist, int n, int* __restrict__ blockTot) {
    __shared__ int sdata[256];
    int base = blockIdx.x * 1024;
    int t = threadIdx.x;
    int i0 = base + t * 4;
    int v0 = (i0 + 0 < n) ? hist[i0 + 0] : 0;
    int v1 = (i0 + 1 < n) ? hist[i0 + 1] : 0;
    int v2 = (i0 + 2 < n) ? hist[i0 + 2] : 0;
    int v3 = (i0 + 3 < n) ? hist[i0 + 3] : 0;
    sdata[t] = v0 + v1 + v2 + v3;
    __syncthreads();
    for (int off = 1; off < 256; off <<= 1) {
        int x = (t >= off) ? sdata[t - off] : 0;
        __syncthreads();
        sdata[t] += x;
        __syncthreads();
    }
    if (t == 255) blockTot[blockIdx.x] = sdata[255];
}

__global__ void scanB(int* __restrict__ blockTot, int nb) {
    int lane = threadIdx.x;  // 64 threads
    int carry = 0;
    for (int base = 0; base < nb; base += 64) {
        int i = base + lane;
        int v = (i < nb) ? blockTot[i] : 0;
        int incl = v;
        #pragma unroll
        for (int off = 1; off < 64; off <<= 1) {
            int t = __shfl_up(incl, off);
            if (lane >= off) incl += t;
        }
        if (i < nb) blockTot[i] = carry + incl - v;
        carry += __shfl(incl, 63);
    }
}

__global__ void scanC(int* __restrict__ hist, int n, const int* __restrict__ blockBase) {
    __shared__ int sdata[256];
    int base = blockIdx.x * 1024;
    int t = threadIdx.x;
    int i0 = base + t * 4;
    int v0 = (i0 + 0 < n) ? hist[i0 + 0] : 0;
    int v1 = (i0 + 1 < n) ? hist[i0 + 1] : 0;
    int v2 = (i0 + 2 < n) ? hist[i0 + 2] : 0;
    int v3 = (i0 + 3 < n) ? hist[i0 + 3] : 0;
    sdata[t] = v0 + v1 + v2 + v3;
    __syncthreads();
    for (int off = 1; off < 256; off <<= 1) {
        int x = (t >= off) ? sdata[t - off] : 0;
        __syncthreads();
        sdata[t] += x;
        __syncthreads();
    }
    int ebase = blockBase[blockIdx.x] + ((t > 0) ? sdata[t - 1] : 0);
    if (i0 + 0 < n) hist[i0 + 0] = ebase;
    if (i0 + 1 < n) hist[i0 + 1] = ebase + v0;
    if (i0 + 2 < n) hist[i0 + 2] = ebase + v0 + v1;
    if (i0 + 3 < n) hist[i0 + 3] = ebase + v0 + v1 + v2;
}

// ---------- scatter r into key-sorted order ----------

__global__ void scatter_kernel(const float* __restrict__ dirs, const int* __restrict__ pci,
                               const int* __restrict__ nsi, const int* __restrict__ dest,
                               int* __restrict__ offsets, float* __restrict__ sortedR, int P) {
    int i = blockIdx.x * blockDim.x + threadIdx.x;
    if (i >= P) return;
    float x = dirs[3 * i + 0], y = dirs[3 * i + 1], z = dirs[3 * i + 2];
    float r2 = x * x + y * y + z * z;
    if (r2 >= RCUT * RCUT) return;
    float r = sqrtf(r2);
    int key = dest[pci[i]] * NSPEC + nsi[i];
    int pos = atomicAdd(&offsets[key], 1);
    sortedR[pos] = r;
}

// ---------- accumulate: register run-length accumulation, rare LDS flushes ----------

#define FLUSH(kk)                                                                   \
    do {                                                                            \
        float* _b = smem + ((kk) >> 2) * LDSTRIDE + ((kk) & 3);                     \
        _Pragma("unroll") for (int j = 0; j < 12; ++j) {                            \
            atomicAdd(_b + j * 4, acc[j]); acc[j] = 0.f; }                          \
        _Pragma("unroll") for (int j = 0; j < 10; ++j) {                            \
            atomicAdd(_b + 48 + j * 4, acc[12 + j]); acc[12 + j] = 0.f; }           \
        _Pragma("unroll") for (int j = 0; j < 8; ++j) {                             \
            atomicAdd(_b + 88 + j * 4, acc[22 + j]); acc[22 + j] = 0.f; }           \
        _Pragma("unroll") for (int j = 0; j < 6; ++j) {                             \
            atomicAdd(_b + 120 + j * 4, acc[30 + j]); acc[30 + j] = 0.f; }          \
    } while (0)

__global__ void __launch_bounds__(256) accum_kernel(
        const int* __restrict__ offs /* end offsets per key bin */,
        const float* __restrict__ sortedR,
        float* __restrict__ out, int NC, int NK) {
    __shared__ float smem[RPB * LDSTRIDE];
    __shared__ int offsEnd[BPB];

    int tid = threadIdx.x;
    int keyBase = blockIdx.x * BPB;
    int rowBase = blockIdx.x * RPB;

    for (int i = tid; i < RPB * LDSTRIDE; i += 256) smem[i] = 0.f;
    for (int i = tid; i < BPB; i += 256) offsEnd[i] = offs[min(keyBase + i, NK - 1)];
    __syncthreads();

    int pairStart = (keyBase == 0) ? 0 : offs[keyBase - 1];
    int pairEnd = offsEnd[BPB - 1];
    int total = pairEnd - pairStart;
    int chunk = (total + 255) >> 8;
    int myStart = pairStart + tid * chunk;
    int myEnd = min(myStart + chunk, pairEnd);

    float acc[36];
    #pragma unroll
    for (int j = 0; j < 36; ++j) acc[j] = 0.f;

    if (myStart < myEnd) {
        // first k with offsEnd[k] > myStart
        int lo = 0, hi = BPB;
        while (lo < hi) {
            int mid = (lo + hi) >> 1;
            if (offsEnd[mid] > myStart) hi = mid; else lo = mid + 1;
        }
        int k = lo;
        bool touched = false;
        for (int p = myStart; p < myEnd; ++p) {
            while (p >= offsEnd[k]) {
                if (touched) { FLUSH(k); touched = false; }
                ++k;
            }
            float r = sortedR[p];
            float r2 = r * r;
            float fc = 0.5f * (__cosf(0.6283185307179586f * r) + 1.0f);  // pi/RCUT
            float q = __expf(-r2 * (1.0f / (RCUT * RCUT)));
            float rl = fc, e = q;
            #pragma unroll
            for (int n = 0; n < 12; ++n) { acc[n] = fmaf(rl, e, acc[n]); e *= q; }
            rl *= r; e = q;
            #pragma unroll
            for (int n = 0; n < 10; ++n) { acc[12 + n] = fmaf(rl, e, acc[12 + n]); e *= q; }
            rl *= r; e = q;
            #pragma unroll
            for (int n = 0; n < 8; ++n) { acc[22 + n] = fmaf(rl, e, acc[22 + n]); e *= q; }
            rl *= r; e = q;
            #pragma unroll
            for (int n = 0; n < 6; ++n) { acc[30 + n] = fmaf(rl, e, acc[30 + n]); e *= q; }
            touched = true;
        }
        if (touched) FLUSH(k);
    }
    __syncthreads();

    int nRows = min(RPB, NC - rowBase);
    int lim = nRows * NFEAT;
    float* obase = out + (size_t)rowBase * NFEAT;
    for (int i = tid; i < lim; i += 256) {
        int row = i / NFEAT;
        int col = i - row * NFEAT;
        obase[i] = smem[row * LDSTRIDE + col];
    }
}

// ---------- fallback: direct atomic scatter ----------

__global__ void pair_kernel(const float* __restrict__ dirs,
                            const int* __restrict__ pci,
                            const int* __restrict__ nsi,
                            const int* __restrict__ dest,
                            float* __restrict__ out, int P) {
    int i = blockIdx.x * blockDim.x + threadIdx.x;
    if (i >= P) return;
    float x = dirs[3 * i + 0], y = dirs[3 * i + 1], z = dirs[3 * i + 2];
    float r2 = x * x + y * y + z * z;
    float r = sqrtf(r2);
    if (r >= RCUT) return;
    float fc = 0.5f * (cosf(3.14159265358979323846f * r * (1.0f / RCUT)) + 1.0f);
    float q = expf(-r2 * (1.0f / (RCUT * RCUT)));
    int rowb = dest[pci[i]] * NFEAT;
    int s = nsi[i];
    float* o = out + rowb + s;
    float rl = fc;
    const int nmax[4] = {12, 10, 8, 6};
    const int offl[4] = {0, 48, 88, 120};
    #pragma unroll
    for (int l = 0; l < 4; ++l) {
        float e = q;
        for (int n = 0; n < nmax[l]; ++n) { atomicAdd(o + offl[l] + n * NSPEC, rl * e); e *= q; }
        rl *= r;
    }
}

extern "C" void kernel_launch(void* const* d_in, const int* in_sizes, int n_in,
                              void* d_out, int out_size, void* d_ws, size_t ws_size,
                              hipStream_t stream) {
    const float* dirs = (const float*)d_in[0];
    const int* pci = (const int*)d_in[1];
    const int* nsi = (const int*)d_in[2];
    const int* cs = (const int*)d_in[3];
    int P = in_sizes[1];
    int NC = in_sizes[3];
    float* out = (float*)d_out;

    int nChunks = (NC + 255) / 256;
    int NK = NC * NSPEC;
    int NB = (NK + 1023) / 1024;

    // ws layout (ints)
    int* chunkCounts  = (int*)d_ws;                      // nChunks*4
    int* chunkOffsets = chunkCounts + nChunks * NSPEC;   // nChunks*4
    int* dest         = chunkOffsets + nChunks * NSPEC;  // NC
    int* hist         = dest + NC;                       // NK (becomes end-offsets)
    int* blockTot     = hist + NK;                       // NB
    float* sortedR    = (float*)(blockTot + NB);         // P

    size_t need = ((size_t)(2 * nChunks * NSPEC) + (size_t)NC + (size_t)NK + NB + (size_t)P)
                  * sizeof(int);

    // center -> sorted-row map
    count_kernel<<<nChunks, 256, 0, stream>>>(cs, NC, chunkCounts);
    scanP_kernel<<<1, 256, 0, stream>>>(chunkCounts, nChunks, chunkOffsets);
    dest_kernel<<<nChunks, 256, 0, stream>>>(cs, NC, chunkOffsets, dest);

    if (ws_size >= need) {
        zero_i32<<<(NK + 255) / 256, 256, 0, stream>>>(hist, NK);
        hist_kernel<<<(P + 255) / 256, 256, 0, stream>>>(dirs, pci, nsi, dest, hist, P);
        scanA<<<NB, 256, 0, stream>>>(hist, NK, blockTot);
        scanB<<<1, 64, 0, stream>>>(blockTot, NB);
        scanC<<<NB, 256, 0, stream>>>(hist, NK, blockTot);
        scatter_kernel<<<(P + 255) / 256, 256, 0, stream>>>(dirs, pci, nsi, dest, hist, sortedR, P);
        accum_kernel<<<(NC + RPB - 1) / RPB, 256, 0, stream>>>(hist, sortedR, out, NC, NK);
    } else {
        zero_f32<<<2048, 256, 0, stream>>>(out, out_size);
        pair_kernel<<<(P + 255) / 256, 256, 0, stream>>>(dirs, pci, nsi, dest, out, P);
    }
}

// Round 6
// 218.194 us; speedup vs baseline: 2.8482x; 1.6441x over previous
//
#include <hip/hip_runtime.h>
#include <hip/hip_bf16.h>

#define NSPEC 4
#define NFEAT 144
#define RCUT 5.0f
#define RPB 64                 // dest-rows per accum block (256 threads = 256 bins)
#define SMSTRIDE 37            // 36 basis values + 1 pad

// ---------- utility ----------

__global__ void zero_f32(float* __restrict__ out, int n) {
    int n4 = n >> 2;
    float4* o4 = (float4*)out;
    for (int i = blockIdx.x * blockDim.x + threadIdx.x; i < n4; i += gridDim.x * blockDim.x)
        o4[i] = make_float4(0.f, 0.f, 0.f, 0.f);
    int tail = n & 3;
    if (blockIdx.x == 0 && threadIdx.x < tail) out[n4 * 4 + threadIdx.x] = 0.f;
}

// ---------- stable counting-sort rank of centers by species (+ hist zeroing) ----------

__global__ void count_kernel(const int* __restrict__ cs, int n, int* __restrict__ chunkCounts,
                             int* __restrict__ histZero, int histN) {
    __shared__ int cnt[NSPEC];
    if (threadIdx.x < NSPEC) cnt[threadIdx.x] = 0;
    __syncthreads();
    int i = blockIdx.x * blockDim.x + threadIdx.x;
    if (i < n) atomicAdd(&cnt[cs[i]], 1);
    // fold the hist zeroing pass in here (saves a dispatch)
    if (histZero) {
        for (int j = i; j < histN; j += gridDim.x * blockDim.x) histZero[j] = 0;
    }
    __syncthreads();
    if (threadIdx.x < NSPEC) chunkCounts[blockIdx.x * NSPEC + threadIdx.x] = cnt[threadIdx.x];
}

__global__ void scanP_kernel(const int* __restrict__ chunkCounts, int nChunks,
                             int* __restrict__ chunkOffsets) {
    __shared__ int totals[NSPEC];
    __shared__ int base4[NSPEC];
    int w = threadIdx.x >> 6;     // species
    int lane = threadIdx.x & 63;
    int carry = 0;
    for (int base = 0; base < nChunks; base += 64) {
        int c = base + lane;
        int v = (c < nChunks) ? chunkCounts[c * NSPEC + w] : 0;
        int incl = v;
        #pragma unroll
        for (int off = 1; off < 64; off <<= 1) {
            int t = __shfl_up(incl, off);
            if (lane >= off) incl += t;
        }
        if (c < nChunks) chunkOffsets[c * NSPEC + w] = carry + incl - v;
        carry += __shfl(incl, 63);
    }
    if (lane == 0) totals[w] = carry;
    __syncthreads();
    if (threadIdx.x == 0) {
        int b = 0;
        for (int s = 0; s < NSPEC; ++s) { base4[s] = b; b += totals[s]; }
    }
    __syncthreads();
    for (int i = threadIdx.x; i < nChunks * NSPEC; i += blockDim.x)
        chunkOffsets[i] += base4[i & (NSPEC - 1)];
}

__global__ void dest_kernel(const int* __restrict__ cs, int n,
                            const int* __restrict__ chunkOffsets, int* __restrict__ dest) {
    __shared__ int waveCnt[4][NSPEC];
    int chunk = blockIdx.x;
    int i = chunk * blockDim.x + threadIdx.x;
    int s = (i < n) ? cs[i] : -1;
    int lane = threadIdx.x & 63;
    int wave = threadIdx.x >> 6;

    int lanePrefix = 0;
    for (int sp = 0; sp < NSPEC; ++sp) {
        unsigned long long b = __ballot(s == sp);
        if (lane == 0) waveCnt[wave][sp] = __popcll(b);
        if (sp == s) lanePrefix = __popcll(b & ((1ull << lane) - 1ull));
    }
    __syncthreads();
    if (i < n) {
        int wp = 0;
        for (int w = 0; w < wave; ++w) wp += waveCnt[w][s];
        dest[i] = chunkOffsets[chunk * NSPEC + s] + wp + lanePrefix;
    }
}

// ---------- pass 1: histogram over 4*NC key bins (key = destRow*4 + species) ----------

__global__ void hist_kernel(const float* __restrict__ dirs, const int* __restrict__ pci,
                            const int* __restrict__ nsi, const int* __restrict__ dest,
                            int* __restrict__ hist, int P) {
    int i = blockIdx.x * blockDim.x + threadIdx.x;
    if (i >= P) return;
    float x = dirs[3 * i + 0], y = dirs[3 * i + 1], z = dirs[3 * i + 2];
    float r2 = x * x + y * y + z * z;
    if (r2 >= RCUT * RCUT) return;
    int key = dest[pci[i]] * NSPEC + nsi[i];
    atomicAdd(&hist[key], 1);
}

// ---------- hierarchical exclusive scan over NK bins ----------

__global__ void scanA(const int* __restrict__ hist, int n, int* __restrict__ blockTot) {
    __shared__ int sdata[256];
    int base = blockIdx.x * 1024;
    int t = threadIdx.x;
    int i0 = base + t * 4;
    int v0 = (i0 + 0 < n) ? hist[i0 + 0] : 0;
    int v1 = (i0 + 1 < n) ? hist[i0 + 1] : 0;
    int v2 = (i0 + 2 < n) ? hist[i0 + 2] : 0;
    int v3 = (i0 + 3 < n) ? hist[i0 + 3] : 0;
    sdata[t] = v0 + v1 + v2 + v3;
    __syncthreads();
    for (int off = 1; off < 256; off <<= 1) {
        int x = (t >= off) ? sdata[t - off] : 0;
        __syncthreads();
        sdata[t] += x;
        __syncthreads();
    }
    if (t == 255) blockTot[blockIdx.x] = sdata[255];
}

__global__ void scanB(int* __restrict__ blockTot, int nb) {
    int lane = threadIdx.x;  // 64 threads
    int carry = 0;
    for (int base = 0; base < nb; base += 64) {
        int i = base + lane;
        int v = (i < nb) ? blockTot[i] : 0;
        int incl = v;
        #pragma unroll
        for (int off = 1; off < 64; off <<= 1) {
            int t = __shfl_up(incl, off);
            if (lane >= off) incl += t;
        }
        if (i < nb) blockTot[i] = carry + incl - v;
        carry += __shfl(incl, 63);
    }
}

__global__ void scanC(int* __restrict__ hist, int n, const int* __restrict__ blockBase) {
    __shared__ int sdata[256];
    int base = blockIdx.x * 1024;
    int t = threadIdx.x;
    int i0 = base + t * 4;
    int v0 = (i0 + 0 < n) ? hist[i0 + 0] : 0;
    int v1 = (i0 + 1 < n) ? hist[i0 + 1] : 0;
    int v2 = (i0 + 2 < n) ? hist[i0 + 2] : 0;
    int v3 = (i0 + 3 < n) ? hist[i0 + 3] : 0;
    sdata[t] = v0 + v1 + v2 + v3;
    __syncthreads();
    for (int off = 1; off < 256; off <<= 1) {
        int x = (t >= off) ? sdata[t - off] : 0;
        __syncthreads();
        sdata[t] += x;
        __syncthreads();
    }
    int ebase = blockBase[blockIdx.x] + ((t > 0) ? sdata[t - 1] : 0);
    if (i0 + 0 < n) hist[i0 + 0] = ebase;
    if (i0 + 1 < n) hist[i0 + 1] = ebase + v0;
    if (i0 + 2 < n) hist[i0 + 2] = ebase + v0 + v1;
    if (i0 + 3 < n) hist[i0 + 3] = ebase + v0 + v1 + v2;
}

// ---------- scatter r into key-sorted order ----------

__global__ void scatter_kernel(const float* __restrict__ dirs, const int* __restrict__ pci,
                               const int* __restrict__ nsi, const int* __restrict__ dest,
                               int* __restrict__ offsets, float* __restrict__ sortedR, int P) {
    int i = blockIdx.x * blockDim.x + threadIdx.x;
    if (i >= P) return;
    float x = dirs[3 * i + 0], y = dirs[3 * i + 1], z = dirs[3 * i + 2];
    float r2 = x * x + y * y + z * z;
    if (r2 >= RCUT * RCUT) return;
    float r = sqrtf(r2);
    int key = dest[pci[i]] * NSPEC + nsi[i];
    int pos = atomicAdd(&offsets[key], 1);
    sortedR[pos] = r;
}

// ---------- accumulate: one thread = one (row,species) bin; no atomics anywhere ----------

__global__ void __launch_bounds__(256, 4) accum_kernel(
        const int* __restrict__ offs /* end offsets per key bin */,
        const float* __restrict__ sortedR,
        float* __restrict__ out, int NC, int NK) {
    __shared__ float sm[256 * SMSTRIDE];

    int tid = threadIdx.x;
    int k = blockIdx.x * 256 + tid;          // my key bin
    int rowBase = blockIdx.x * RPB;

    float acc[36];
    #pragma unroll
    for (int j = 0; j < 36; ++j) acc[j] = 0.f;

    if (k < NK) {
        int start = (k == 0) ? 0 : offs[k - 1];
        int end = offs[k];
        for (int p = start; p < end; ++p) {
            float r = sortedR[p];
            float r2 = r * r;
            float fc = 0.5f * (__cosf(0.6283185307179586f * r) + 1.0f);  // pi/RCUT
            float q = __expf(-r2 * 0.04f);                                // exp(-r^2/25)
            float q2 = q * q;
            float bq[12];                    // bq[n] = q^(n+1), two independent x q^2 chains
            bq[0] = q; bq[1] = q2;
            #pragma unroll
            for (int n = 2; n < 12; ++n) bq[n] = bq[n - 2] * q2;
            float a0 = fc, a1 = fc * r, a2 = a1 * r, a3 = a2 * r;
            #pragma unroll
            for (int n = 0; n < 12; ++n) acc[n]      = fmaf(a0, bq[n], acc[n]);
            #pragma unroll
            for (int n = 0; n < 10; ++n) acc[12 + n] = fmaf(a1, bq[n], acc[12 + n]);
            #pragma unroll
            for (int n = 0; n < 8; ++n)  acc[22 + n] = fmaf(a2, bq[n], acc[22 + n]);
            #pragma unroll
            for (int n = 0; n < 6; ++n)  acc[30 + n] = fmaf(a3, bq[n], acc[30 + n]);
        }
    }

    // stage contiguously: sm[tid][j]; every (row,species) covered -> no zero-init needed
    float* myRow = sm + tid * SMSTRIDE;
    #pragma unroll
    for (int j = 0; j < 36; j += 4)
        *(float4*)(myRow + j) = make_float4(acc[j], acc[j + 1], acc[j + 2], acc[j + 3]);
    __syncthreads();

    // coalesced linear write: rows are dest-ordered, block covers rows [rowBase, rowBase+64)
    int nRows = min(RPB, NC - rowBase);
    int lim = nRows * NFEAT;
    float* obase = out + (size_t)rowBase * NFEAT;
    for (int i = tid; i < lim; i += 256) {
        int row = i / NFEAT;
        int col = i - row * NFEAT;
        // col = off_l + 4n + s  ->  staircase index j = col>>2, species s = col&3
        obase[i] = sm[((row << 2) | (col & 3)) * SMSTRIDE + (col >> 2)];
    }
}

// ---------- fallback: direct atomic scatter ----------

__global__ void pair_kernel(const float* __restrict__ dirs,
                            const int* __restrict__ pci,
                            const int* __restrict__ nsi,
                            const int* __restrict__ dest,
                            float* __restrict__ out, int P) {
    int i = blockIdx.x * blockDim.x + threadIdx.x;
    if (i >= P) return;
    float x = dirs[3 * i + 0], y = dirs[3 * i + 1], z = dirs[3 * i + 2];
    float r2 = x * x + y * y + z * z;
    float r = sqrtf(r2);
    if (r >= RCUT) return;
    float fc = 0.5f * (cosf(3.14159265358979323846f * r * (1.0f / RCUT)) + 1.0f);
    float q = expf(-r2 * (1.0f / (RCUT * RCUT)));
    int rowb = dest[pci[i]] * NFEAT;
    int s = nsi[i];
    float* o = out + rowb + s;
    float rl = fc;
    const int nmax[4] = {12, 10, 8, 6};
    const int offl[4] = {0, 48, 88, 120};
    #pragma unroll
    for (int l = 0; l < 4; ++l) {
        float e = q;
        for (int n = 0; n < nmax[l]; ++n) { atomicAdd(o + offl[l] + n * NSPEC, rl * e); e *= q; }
        rl *= r;
    }
}

extern "C" void kernel_launch(void* const* d_in, const int* in_sizes, int n_in,
                              void* d_out, int out_size, void* d_ws, size_t ws_size,
                              hipStream_t stream) {
    const float* dirs = (const float*)d_in[0];
    const int* pci = (const int*)d_in[1];
    const int* nsi = (const int*)d_in[2];
    const int* cs = (const int*)d_in[3];
    int P = in_sizes[1];
    int NC = in_sizes[3];
    float* out = (float*)d_out;

    int nChunks = (NC + 255) / 256;
    int NK = NC * NSPEC;
    int NB = (NK + 1023) / 1024;

    // ws layout (ints)
    int* chunkCounts  = (int*)d_ws;                      // nChunks*4
    int* chunkOffsets = chunkCounts + nChunks * NSPEC;   // nChunks*4
    int* dest         = chunkOffsets + nChunks * NSPEC;  // NC
    int* hist         = dest + NC;                       // NK (becomes end-offsets)
    int* blockTot     = hist + NK;                       // NB
    float* sortedR    = (float*)(blockTot + NB);         // P

    size_t need = ((size_t)(2 * nChunks * NSPEC) + (size_t)NC + (size_t)NK + NB + (size_t)P)
                  * sizeof(int);
    bool sortedPath = (ws_size >= need);

    // center -> sorted-row map (count also zeroes hist when the sorted path is active)
    count_kernel<<<nChunks, 256, 0, stream>>>(cs, NC, chunkCounts,
                                              sortedPath ? hist : (int*)nullptr, NK);
    scanP_kernel<<<1, 256, 0, stream>>>(chunkCounts, nChunks, chunkOffsets);
    dest_kernel<<<nChunks, 256, 0, stream>>>(cs, NC, chunkOffsets, dest);

    if (sortedPath) {
        hist_kernel<<<(P + 255) / 256, 256, 0, stream>>>(dirs, pci, nsi, dest, hist, P);
        scanA<<<NB, 256, 0, stream>>>(hist, NK, blockTot);
        scanB<<<1, 64, 0, stream>>>(blockTot, NB);
        scanC<<<NB, 256, 0, stream>>>(hist, NK, blockTot);
        scatter_kernel<<<(P + 255) / 256, 256, 0, stream>>>(dirs, pci, nsi, dest, hist, sortedR, P);
        accum_kernel<<<(NC + RPB - 1) / RPB, 256, 0, stream>>>(hist, sortedR, out, NC, NK);
    } else {
        zero_f32<<<2048, 256, 0, stream>>>(out, out_size);
        pair_kernel<<<(P + 255) / 256, 256, 0, stream>>>(dirs, pci, nsi, dest, out, P);
    }
}

// Round 7
// 90.748 us; speedup vs baseline: 6.8481x; 2.4044x over previous
//
#include <hip/hip_runtime.h>
#include <hip/hip_bf16.h>

#define NSPEC 4
#define NFEAT 144
#define RCUT 5.0f
#define RPB 64                 // dest-rows per bucket / accum block
#define MAXB 1568              // max buckets (NC <= 100352)
#define CAP 1536               // pairs capacity per bucket (avg ~1150, +11 sigma)
#define CHUNK 8192             // pairs per partition block
#define IPT (CHUNK / 256)      // items per thread = 32
#define SMSTRIDE 37            // 36 basis values + 1 pad

// ---------- utility ----------

__global__ void zero_f32(float* __restrict__ out, int n) {
    int n4 = n >> 2;
    float4* o4 = (float4*)out;
    for (int i = blockIdx.x * blockDim.x + threadIdx.x; i < n4; i += gridDim.x * blockDim.x)
        o4[i] = make_float4(0.f, 0.f, 0.f, 0.f);
    int tail = n & 3;
    if (blockIdx.x == 0 && threadIdx.x < tail) out[n4 * 4 + threadIdx.x] = 0.f;
}

// ---------- stable counting-sort rank of centers by species (+ cursor zeroing) ----------

__global__ void count_kernel(const int* __restrict__ cs, int n, int* __restrict__ chunkCounts,
                             int* __restrict__ zeroPtr, int zeroN) {
    __shared__ int cnt[NSPEC];
    if (threadIdx.x < NSPEC) cnt[threadIdx.x] = 0;
    __syncthreads();
    int i = blockIdx.x * blockDim.x + threadIdx.x;
    if (i < n) atomicAdd(&cnt[cs[i]], 1);
    if (zeroPtr) {
        for (int j = i; j < zeroN; j += gridDim.x * blockDim.x) zeroPtr[j] = 0;
    }
    __syncthreads();
    if (threadIdx.x < NSPEC) chunkCounts[blockIdx.x * NSPEC + threadIdx.x] = cnt[threadIdx.x];
}

__global__ void scanP_kernel(const int* __restrict__ chunkCounts, int nChunks,
                             int* __restrict__ chunkOffsets) {
    __shared__ int totals[NSPEC];
    __shared__ int base4[NSPEC];
    int w = threadIdx.x >> 6;     // species
    int lane = threadIdx.x & 63;
    int carry = 0;
    for (int base = 0; base < nChunks; base += 64) {
        int c = base + lane;
        int v = (c < nChunks) ? chunkCounts[c * NSPEC + w] : 0;
        int incl = v;
        #pragma unroll
        for (int off = 1; off < 64; off <<= 1) {
            int t = __shfl_up(incl, off);
            if (lane >= off) incl += t;
        }
        if (c < nChunks) chunkOffsets[c * NSPEC + w] = carry + incl - v;
        carry += __shfl(incl, 63);
    }
    if (lane == 0) totals[w] = carry;
    __syncthreads();
    if (threadIdx.x == 0) {
        int b = 0;
        for (int s = 0; s < NSPEC; ++s) { base4[s] = b; b += totals[s]; }
    }
    __syncthreads();
    for (int i = threadIdx.x; i < nChunks * NSPEC; i += blockDim.x)
        chunkOffsets[i] += base4[i & (NSPEC - 1)];
}

__global__ void dest_kernel(const int* __restrict__ cs, int n,
                            const int* __restrict__ chunkOffsets, int* __restrict__ dest) {
    __shared__ int waveCnt[4][NSPEC];
    int chunk = blockIdx.x;
    int i = chunk * blockDim.x + threadIdx.x;
    int s = (i < n) ? cs[i] : -1;
    int lane = threadIdx.x & 63;
    int wave = threadIdx.x >> 6;

    int lanePrefix = 0;
    for (int sp = 0; sp < NSPEC; ++sp) {
        unsigned long long b = __ballot(s == sp);
        if (lane == 0) waveCnt[wave][sp] = __popcll(b);
        if (sp == s) lanePrefix = __popcll(b & ((1ull << lane) - 1ull));
    }
    __syncthreads();
    if (i < n) {
        int wp = 0;
        for (int w = 0; w < wave; ++w) wp += waveCnt[w][s];
        dest[i] = chunkOffsets[chunk * NSPEC + s] + wp + lanePrefix;
    }
}

// ---------- partition: LDS counting-sort of 8192 pairs into row-block buckets ----------
// payload u: bits[31:8] = r (low 8 mantissa bits replaced), bits[7:2] = row&63,
// bits[1:0] = species.

__global__ void __launch_bounds__(256) partition_kernel(
        const float* __restrict__ dirs, const int* __restrict__ pci,
        const int* __restrict__ nsi, const int* __restrict__ dest,
        int* __restrict__ gCursor, unsigned* __restrict__ gBucket, int P, int nbk) {
    __shared__ unsigned sSort[CHUNK];
    __shared__ int sHist[MAXB];
    __shared__ int sOffs[MAXB];
    __shared__ int sWaveTot[4];

    int tid = threadIdx.x;
    int base = blockIdx.x * CHUNK;

    for (int i = tid; i < nbk; i += 256) sHist[i] = 0;
    __syncthreads();

    unsigned uu[IPT];
    int bb[IPT];
    #pragma unroll
    for (int j = 0; j < IPT; ++j) {
        int i = base + j * 256 + tid;
        int bkt = -1; unsigned u = 0;
        if (i < P) {
            float x = dirs[3 * i + 0], y = dirs[3 * i + 1], z = dirs[3 * i + 2];
            float r2 = x * x + y * y + z * z;
            if (r2 < RCUT * RCUT) {
                float r = sqrtf(r2);
                int row = dest[pci[i]];
                bkt = row >> 6;
                u = (__float_as_uint(r) & 0xFFFFFF00u) | ((unsigned)(row & 63) << 2) |
                    (unsigned)nsi[i];
                atomicAdd(&sHist[bkt], 1);
            }
        }
        uu[j] = u; bb[j] = bkt;
    }
    __syncthreads();

    // block exclusive scan of sHist[0..nbk) into sOffs
    int seg = (nbk + 255) >> 8;
    int s0 = tid * seg;
    int run = 0;
    for (int k = 0; k < seg; ++k) {
        int idx = s0 + k;
        if (idx < nbk) { sOffs[idx] = run; run += sHist[idx]; }
    }
    int lane = tid & 63, wv = tid >> 6;
    int incl = run;
    #pragma unroll
    for (int off = 1; off < 64; off <<= 1) {
        int t = __shfl_up(incl, off);
        if (lane >= off) incl += t;
    }
    if (lane == 63) sWaveTot[wv] = incl;
    __syncthreads();
    int wbase = 0;
    for (int w = 0; w < wv; ++w) wbase += sWaveTot[w];
    int exc = wbase + incl - run;
    for (int k = 0; k < seg; ++k) {
        int idx = s0 + k;
        if (idx < nbk) sOffs[idx] += exc;
    }
    __syncthreads();

    // scatter into LDS sorted order (sOffs becomes end-cursor per bucket)
    #pragma unroll
    for (int j = 0; j < IPT; ++j) {
        if (bb[j] >= 0) {
            int pos = atomicAdd(&sOffs[bb[j]], 1);
            sSort[pos] = uu[j];
        }
    }
    __syncthreads();

    // flush each bucket's contiguous run to its global region
    for (int b = tid; b < nbk; b += 256) {
        int c = sHist[b];
        if (!c) continue;
        int start = sOffs[b] - c;
        int g = atomicAdd(&gCursor[b], c);
        int lim = min(c, CAP - g);          // safety clamp, never expected to trigger
        unsigned* dst = gBucket + (size_t)b * CAP + g;
        for (int k = 0; k < lim; ++k) dst[k] = sSort[start + k];
    }
}

// ---------- accumulate: bucket -> LDS sort to 256 bins -> one thread per bin ----------

__global__ void __launch_bounds__(256) accum_kernel(
        const int* __restrict__ gCursor, const unsigned* __restrict__ gBucket,
        float* __restrict__ out, int NC) {
    __shared__ unsigned sRaw[CAP];
    __shared__ unsigned sSort[CAP];
    __shared__ int sHist[256];
    __shared__ int sOff[256];
    __shared__ int sWaveTot[4];
    __shared__ float sStage[256 * SMSTRIDE];

    int tid = threadIdx.x;
    int b = blockIdx.x;
    int rowBase = b * RPB;
    int n = min(gCursor[b], CAP);
    const unsigned* src = gBucket + (size_t)b * CAP;

    sHist[tid] = 0;
    __syncthreads();

    for (int i = tid; i < n; i += 256) {
        unsigned u = src[i];
        sRaw[i] = u;
        atomicAdd(&sHist[u & 255u], 1);
    }
    __syncthreads();

    // exclusive scan of 256 bins
    int lane = tid & 63, wv = tid >> 6;
    int v = sHist[tid];
    int incl = v;
    #pragma unroll
    for (int off = 1; off < 64; off <<= 1) {
        int t = __shfl_up(incl, off);
        if (lane >= off) incl += t;
    }
    if (lane == 63) sWaveTot[wv] = incl;
    __syncthreads();
    int wbase = 0;
    for (int w = 0; w < wv; ++w) wbase += sWaveTot[w];
    sOff[tid] = wbase + incl - v;
    __syncthreads();

    // scatter within LDS (sOff becomes end-cursor)
    for (int i = tid; i < n; i += 256) {
        unsigned u = sRaw[i];
        int pos = atomicAdd(&sOff[u & 255u], 1);
        sSort[pos] = u;
    }
    __syncthreads();

    // my bin = tid = (rowLocal<<2)|species
    int end = sOff[tid], start = end - sHist[tid];
    float acc[36];
    #pragma unroll
    for (int j = 0; j < 36; ++j) acc[j] = 0.f;

    for (int p = start; p < end; ++p) {
        unsigned u = sSort[p];
        float r = __uint_as_float(u & 0xFFFFFF00u);
        float r2 = r * r;
        float fc = 0.5f * (__cosf(0.6283185307179586f * r) + 1.0f);  // cos(pi*r/RCUT)
        float q = __expf(-r2 * 0.04f);                                // exp(-r^2/25)
        float q2 = q * q;
        float bq[12];  // bq[n] = q^(n+1), two independent x q^2 chains
        bq[0] = q; bq[1] = q2;
        #pragma unroll
        for (int nn = 2; nn < 12; ++nn) bq[nn] = bq[nn - 2] * q2;
        float a0 = fc, a1 = fc * r, a2 = a1 * r, a3 = a2 * r;
        #pragma unroll
        for (int nn = 0; nn < 12; ++nn) acc[nn]      = fmaf(a0, bq[nn], acc[nn]);
        #pragma unroll
        for (int nn = 0; nn < 10; ++nn) acc[12 + nn] = fmaf(a1, bq[nn], acc[12 + nn]);
        #pragma unroll
        for (int nn = 0; nn < 8; ++nn)  acc[22 + nn] = fmaf(a2, bq[nn], acc[22 + nn]);
        #pragma unroll
        for (int nn = 0; nn < 6; ++nn)  acc[30 + nn] = fmaf(a3, bq[nn], acc[30 + nn]);
    }

    // stage contiguously; every (row,species) bin covered -> no zero-init of out needed
    float* myRow = sStage + tid * SMSTRIDE;
    #pragma unroll
    for (int j = 0; j < 36; j += 4)
        *(float4*)(myRow + j) = make_float4(acc[j], acc[j + 1], acc[j + 2], acc[j + 3]);
    __syncthreads();

    int nRows = min(RPB, NC - rowBase);
    int lim = nRows * NFEAT;
    float* obase = out + (size_t)rowBase * NFEAT;
    for (int i = tid; i < lim; i += 256) {
        int row = i / NFEAT;
        int col = i - row * NFEAT;
        obase[i] = sStage[((row << 2) | (col & 3)) * SMSTRIDE + (col >> 2)];
    }
}

// ---------- fallback: direct atomic scatter ----------

__global__ void pair_kernel(const float* __restrict__ dirs,
                            const int* __restrict__ pci,
                            const int* __restrict__ nsi,
                            const int* __restrict__ dest,
                            float* __restrict__ out, int P) {
    int i = blockIdx.x * blockDim.x + threadIdx.x;
    if (i >= P) return;
    float x = dirs[3 * i + 0], y = dirs[3 * i + 1], z = dirs[3 * i + 2];
    float r2 = x * x + y * y + z * z;
    float r = sqrtf(r2);
    if (r >= RCUT) return;
    float fc = 0.5f * (cosf(3.14159265358979323846f * r * (1.0f / RCUT)) + 1.0f);
    float q = expf(-r2 * (1.0f / (RCUT * RCUT)));
    int rowb = dest[pci[i]] * NFEAT;
    int s = nsi[i];
    float* o = out + rowb + s;
    float rl = fc;
    const int nmax[4] = {12, 10, 8, 6};
    const int offl[4] = {0, 48, 88, 120};
    #pragma unroll
    for (int l = 0; l < 4; ++l) {
        float e = q;
        for (int n = 0; n < nmax[l]; ++n) { atomicAdd(o + offl[l] + n * NSPEC, rl * e); e *= q; }
        rl *= r;
    }
}

extern "C" void kernel_launch(void* const* d_in, const int* in_sizes, int n_in,
                              void* d_out, int out_size, void* d_ws, size_t ws_size,
                              hipStream_t stream) {
    const float* dirs = (const float*)d_in[0];
    const int* pci = (const int*)d_in[1];
    const int* nsi = (const int*)d_in[2];
    const int* cs = (const int*)d_in[3];
    int P = in_sizes[1];
    int NC = in_sizes[3];
    float* out = (float*)d_out;

    int nChunks = (NC + 255) / 256;
    int nbk = (NC + RPB - 1) / RPB;

    // ws layout (ints)
    int* chunkCounts  = (int*)d_ws;                      // nChunks*4
    int* chunkOffsets = chunkCounts + nChunks * NSPEC;   // nChunks*4
    int* dest         = chunkOffsets + nChunks * NSPEC;  // NC
    int* gCursor      = dest + NC;                       // nbk
    unsigned* gBucket = (unsigned*)(gCursor + nbk);      // nbk*CAP

    size_t need = ((size_t)(2 * nChunks * NSPEC) + (size_t)NC + (size_t)nbk +
                   (size_t)nbk * CAP) * sizeof(int);
    bool fastPath = (ws_size >= need) && (nbk <= MAXB);

    // center -> sorted-row map (count also zeroes gCursor on the fast path)
    count_kernel<<<nChunks, 256, 0, stream>>>(cs, NC, chunkCounts,
                                              fastPath ? gCursor : (int*)nullptr, nbk);
    scanP_kernel<<<1, 256, 0, stream>>>(chunkCounts, nChunks, chunkOffsets);
    dest_kernel<<<nChunks, 256, 0, stream>>>(cs, NC, chunkOffsets, dest);

    if (fastPath) {
        int nPart = (P + CHUNK - 1) / CHUNK;
        partition_kernel<<<nPart, 256, 0, stream>>>(dirs, pci, nsi, dest, gCursor, gBucket,
                                                    P, nbk);
        accum_kernel<<<nbk, 256, 0, stream>>>(gCursor, gBucket, out, NC);
    } else {
        zero_f32<<<2048, 256, 0, stream>>>(out, out_size);
        pair_kernel<<<(P + 255) / 256, 256, 0, stream>>>(dirs, pci, nsi, dest, out, P);
    }
}

// Round 8
// 76.935 us; speedup vs baseline: 8.0776x; 1.1795x over previous
//
#include <hip/hip_runtime.h>
#include <hip/hip_bf16.h>

#define NSPEC 4
#define NFEAT 144
#define RCUT 5.0f
#define RPB 64                 // dest-rows per bucket / accum block
#define MAXB 1568              // max buckets (NC <= 100352)
#define CAP 1536               // pairs capacity per bucket (avg ~1150)
#define CHUNK 8192             // pairs per partition block
#define PBDIM 1024             // partition block threads (16 waves)
#define IPT (CHUNK / PBDIM)    // items per thread = 8
#define SMSTRIDE 37            // 36 basis values + 1 pad

// ---------- utility ----------

__global__ void zero_f32(float* __restrict__ out, int n) {
    int n4 = n >> 2;
    float4* o4 = (float4*)out;
    for (int i = blockIdx.x * blockDim.x + threadIdx.x; i < n4; i += gridDim.x * blockDim.x)
        o4[i] = make_float4(0.f, 0.f, 0.f, 0.f);
    int tail = n & 3;
    if (blockIdx.x == 0 && threadIdx.x < tail) out[n4 * 4 + threadIdx.x] = 0.f;
}

// ---------- stable counting-sort rank of centers by species (+ cursor zeroing) ----------

__global__ void count_kernel(const int* __restrict__ cs, int n, int* __restrict__ chunkCounts,
                             int* __restrict__ zeroPtr, int zeroN) {
    __shared__ int cnt[NSPEC];
    if (threadIdx.x < NSPEC) cnt[threadIdx.x] = 0;
    __syncthreads();
    int i = blockIdx.x * blockDim.x + threadIdx.x;
    if (i < n) atomicAdd(&cnt[cs[i]], 1);
    if (zeroPtr) {
        for (int j = i; j < zeroN; j += gridDim.x * blockDim.x) zeroPtr[j] = 0;
    }
    __syncthreads();
    if (threadIdx.x < NSPEC) chunkCounts[blockIdx.x * NSPEC + threadIdx.x] = cnt[threadIdx.x];
}

__global__ void scanP_kernel(const int* __restrict__ chunkCounts, int nChunks,
                             int* __restrict__ chunkOffsets) {
    __shared__ int totals[NSPEC];
    __shared__ int base4[NSPEC];
    int w = threadIdx.x >> 6;     // species
    int lane = threadIdx.x & 63;
    int carry = 0;
    for (int base = 0; base < nChunks; base += 64) {
        int c = base + lane;
        int v = (c < nChunks) ? chunkCounts[c * NSPEC + w] : 0;
        int incl = v;
        #pragma unroll
        for (int off = 1; off < 64; off <<= 1) {
            int t = __shfl_up(incl, off);
            if (lane >= off) incl += t;
        }
        if (c < nChunks) chunkOffsets[c * NSPEC + w] = carry + incl - v;
        carry += __shfl(incl, 63);
    }
    if (lane == 0) totals[w] = carry;
    __syncthreads();
    if (threadIdx.x == 0) {
        int b = 0;
        for (int s = 0; s < NSPEC; ++s) { base4[s] = b; b += totals[s]; }
    }
    __syncthreads();
    for (int i = threadIdx.x; i < nChunks * NSPEC; i += blockDim.x)
        chunkOffsets[i] += base4[i & (NSPEC - 1)];
}

__global__ void dest_kernel(const int* __restrict__ cs, int n,
                            const int* __restrict__ chunkOffsets, int* __restrict__ dest) {
    __shared__ int waveCnt[4][NSPEC];
    int chunk = blockIdx.x;
    int i = chunk * blockDim.x + threadIdx.x;
    int s = (i < n) ? cs[i] : -1;
    int lane = threadIdx.x & 63;
    int wave = threadIdx.x >> 6;

    int lanePrefix = 0;
    for (int sp = 0; sp < NSPEC; ++sp) {
        unsigned long long b = __ballot(s == sp);
        if (lane == 0) waveCnt[wave][sp] = __popcll(b);
        if (sp == s) lanePrefix = __popcll(b & ((1ull << lane) - 1ull));
    }
    __syncthreads();
    if (i < n) {
        int wp = 0;
        for (int w = 0; w < wave; ++w) wp += waveCnt[w][s];
        dest[i] = chunkOffsets[chunk * NSPEC + s] + wp + lanePrefix;
    }
}

// ---------- partition: LDS counting-sort of 8192 pairs into row-block buckets ----------
// payload u: bits[31:8] = r (low 8 mantissa bits replaced), bits[7:2] = row&63,
// bits[1:0] = species. 1024 threads / 16 waves to hide gather+LDS+flush latency.

__global__ void __launch_bounds__(PBDIM) partition_kernel(
        const float* __restrict__ dirs, const int* __restrict__ pci,
        const int* __restrict__ nsi, const int* __restrict__ dest,
        int* __restrict__ gCursor, unsigned* __restrict__ gBucket, int P, int nbk) {
    __shared__ unsigned sSort[CHUNK];
    __shared__ int sHist[MAXB];
    __shared__ int sOffs[MAXB];
    __shared__ int sWaveTot[PBDIM / 64];

    int tid = threadIdx.x;
    int base = blockIdx.x * CHUNK;

    for (int i = tid; i < nbk; i += PBDIM) sHist[i] = 0;
    __syncthreads();

    unsigned uu[IPT];
    int bb[IPT];
    #pragma unroll
    for (int j = 0; j < IPT; ++j) {
        int i = base + j * PBDIM + tid;
        int bkt = -1; unsigned u = 0;
        if (i < P) {
            float x = dirs[3 * i + 0], y = dirs[3 * i + 1], z = dirs[3 * i + 2];
            float r2 = x * x + y * y + z * z;
            if (r2 < RCUT * RCUT) {
                float r = sqrtf(r2);
                int row = dest[pci[i]];
                bkt = row >> 6;
                u = (__float_as_uint(r) & 0xFFFFFF00u) | ((unsigned)(row & 63) << 2) |
                    (unsigned)nsi[i];
                atomicAdd(&sHist[bkt], 1);
            }
        }
        uu[j] = u; bb[j] = bkt;
    }
    __syncthreads();

    // block exclusive scan of sHist[0..nbk) into sOffs
    int seg = (nbk + PBDIM - 1) / PBDIM;
    int s0 = tid * seg;
    int run = 0;
    for (int k = 0; k < seg; ++k) {
        int idx = s0 + k;
        if (idx < nbk) { sOffs[idx] = run; run += sHist[idx]; }
    }
    int lane = tid & 63, wv = tid >> 6;
    int incl = run;
    #pragma unroll
    for (int off = 1; off < 64; off <<= 1) {
        int t = __shfl_up(incl, off);
        if (lane >= off) incl += t;
    }
    if (lane == 63) sWaveTot[wv] = incl;
    __syncthreads();
    int wbase = 0;
    for (int w = 0; w < wv; ++w) wbase += sWaveTot[w];
    int exc = wbase + incl - run;
    for (int k = 0; k < seg; ++k) {
        int idx = s0 + k;
        if (idx < nbk) sOffs[idx] += exc;
    }
    __syncthreads();

    // scatter into LDS sorted order (sOffs becomes end-cursor per bucket)
    #pragma unroll
    for (int j = 0; j < IPT; ++j) {
        if (bb[j] >= 0) {
            int pos = atomicAdd(&sOffs[bb[j]], 1);
            sSort[pos] = uu[j];
        }
    }
    __syncthreads();

    // flush each bucket's contiguous run to its global region
    for (int b = tid; b < nbk; b += PBDIM) {
        int c = sHist[b];
        if (!c) continue;
        int start = sOffs[b] - c;
        int g = atomicAdd(&gCursor[b], c);
        int lim = min(c, CAP - g);          // safety clamp, never expected to trigger
        unsigned* dst = gBucket + (size_t)b * CAP + g;
        for (int k = 0; k < lim; ++k) dst[k] = sSort[start + k];
    }
}

// ---------- accumulate: bucket -> LDS sort to 256 bins -> one thread per bin ----------

__global__ void __launch_bounds__(256) accum_kernel(
        const int* __restrict__ gCursor, const unsigned* __restrict__ gBucket,
        float* __restrict__ out, int NC) {
    __shared__ unsigned sRaw[CAP];
    __shared__ unsigned sSort[CAP];
    __shared__ int sHist[256];
    __shared__ int sOff[256];
    __shared__ int sWaveTot[4];
    __shared__ float sStage[256 * SMSTRIDE];

    int tid = threadIdx.x;
    int b = blockIdx.x;
    int rowBase = b * RPB;
    int n = min(gCursor[b], CAP);
    const unsigned* src = gBucket + (size_t)b * CAP;

    sHist[tid] = 0;
    __syncthreads();

    for (int i = tid; i < n; i += 256) {
        unsigned u = src[i];
        sRaw[i] = u;
        atomicAdd(&sHist[u & 255u], 1);
    }
    __syncthreads();

    // exclusive scan of 256 bins
    int lane = tid & 63, wv = tid >> 6;
    int v = sHist[tid];
    int incl = v;
    #pragma unroll
    for (int off = 1; off < 64; off <<= 1) {
        int t = __shfl_up(incl, off);
        if (lane >= off) incl += t;
    }
    if (lane == 63) sWaveTot[wv] = incl;
    __syncthreads();
    int wbase = 0;
    for (int w = 0; w < wv; ++w) wbase += sWaveTot[w];
    sOff[tid] = wbase + incl - v;
    __syncthreads();

    // scatter within LDS (sOff becomes end-cursor)
    for (int i = tid; i < n; i += 256) {
        unsigned u = sRaw[i];
        int pos = atomicAdd(&sOff[u & 255u], 1);
        sSort[pos] = u;
    }
    __syncthreads();

    // my bin = tid = (rowLocal<<2)|species
    int end = sOff[tid], start = end - sHist[tid];
    float acc[36];
    #pragma unroll
    for (int j = 0; j < 36; ++j) acc[j] = 0.f;

    for (int p = start; p < end; ++p) {
        unsigned u = sSort[p];
        float r = __uint_as_float(u & 0xFFFFFF00u);
        float r2 = r * r;
        float fc = 0.5f * (__cosf(0.6283185307179586f * r) + 1.0f);  // cos(pi*r/RCUT)
        float q = __expf(-r2 * 0.04f);                                // exp(-r^2/25)
        float q2 = q * q;
        float bq[12];  // bq[n] = q^(n+1), two independent x q^2 chains
        bq[0] = q; bq[1] = q2;
        #pragma unroll
        for (int nn = 2; nn < 12; ++nn) bq[nn] = bq[nn - 2] * q2;
        float a0 = fc, a1 = fc * r, a2 = a1 * r, a3 = a2 * r;
        #pragma unroll
        for (int nn = 0; nn < 12; ++nn) acc[nn]      = fmaf(a0, bq[nn], acc[nn]);
        #pragma unroll
        for (int nn = 0; nn < 10; ++nn) acc[12 + nn] = fmaf(a1, bq[nn], acc[12 + nn]);
        #pragma unroll
        for (int nn = 0; nn < 8; ++nn)  acc[22 + nn] = fmaf(a2, bq[nn], acc[22 + nn]);
        #pragma unroll
        for (int nn = 0; nn < 6; ++nn)  acc[30 + nn] = fmaf(a3, bq[nn], acc[30 + nn]);
    }

    // stage contiguously; every (row,species) bin covered -> no zero-init of out needed
    float* myRow = sStage + tid * SMSTRIDE;
    #pragma unroll
    for (int j = 0; j < 36; j += 4)
        *(float4*)(myRow + j) = make_float4(acc[j], acc[j + 1], acc[j + 2], acc[j + 3]);
    __syncthreads();

    int nRows = min(RPB, NC - rowBase);
    int lim = nRows * NFEAT;
    float* obase = out + (size_t)rowBase * NFEAT;
    for (int i = tid; i < lim; i += 256) {
        int row = i / NFEAT;
        int col = i - row * NFEAT;
        obase[i] = sStage[((row << 2) | (col & 3)) * SMSTRIDE + (col >> 2)];
    }
}

// ---------- fallback: direct atomic scatter ----------

__global__ void pair_kernel(const float* __restrict__ dirs,
                            const int* __restrict__ pci,
                            const int* __restrict__ nsi,
                            const int* __restrict__ dest,
                            float* __restrict__ out, int P) {
    int i = blockIdx.x * blockDim.x + threadIdx.x;
    if (i >= P) return;
    float x = dirs[3 * i + 0], y = dirs[3 * i + 1], z = dirs[3 * i + 2];
    float r2 = x * x + y * y + z * z;
    float r = sqrtf(r2);
    if (r >= RCUT) return;
    float fc = 0.5f * (cosf(3.14159265358979323846f * r * (1.0f / RCUT)) + 1.0f);
    float q = expf(-r2 * (1.0f / (RCUT * RCUT)));
    int rowb = dest[pci[i]] * NFEAT;
    int s = nsi[i];
    float* o = out + rowb + s;
    float rl = fc;
    const int nmax[4] = {12, 10, 8, 6};
    const int offl[4] = {0, 48, 88, 120};
    #pragma unroll
    for (int l = 0; l < 4; ++l) {
        float e = q;
        for (int n = 0; n < nmax[l]; ++n) { atomicAdd(o + offl[l] + n * NSPEC, rl * e); e *= q; }
        rl *= r;
    }
}

extern "C" void kernel_launch(void* const* d_in, const int* in_sizes, int n_in,
                              void* d_out, int out_size, void* d_ws, size_t ws_size,
                              hipStream_t stream) {
    const float* dirs = (const float*)d_in[0];
    const int* pci = (const int*)d_in[1];
    const int* nsi = (const int*)d_in[2];
    const int* cs = (const int*)d_in[3];
    int P = in_sizes[1];
    int NC = in_sizes[3];
    float* out = (float*)d_out;

    int nChunks = (NC + 255) / 256;
    int nbk = (NC + RPB - 1) / RPB;

    // ws layout (ints)
    int* chunkCounts  = (int*)d_ws;                      // nChunks*4
    int* chunkOffsets = chunkCounts + nChunks * NSPEC;   // nChunks*4
    int* dest         = chunkOffsets + nChunks * NSPEC;  // NC
    int* gCursor      = dest + NC;                       // nbk
    unsigned* gBucket = (unsigned*)(gCursor + nbk);      // nbk*CAP

    size_t need = ((size_t)(2 * nChunks * NSPEC) + (size_t)NC + (size_t)nbk +
                   (size_t)nbk * CAP) * sizeof(int);
    bool fastPath = (ws_size >= need) && (nbk <= MAXB);

    // center -> sorted-row map (count also zeroes gCursor on the fast path)
    count_kernel<<<nChunks, 256, 0, stream>>>(cs, NC, chunkCounts,
                                              fastPath ? gCursor : (int*)nullptr, nbk);
    scanP_kernel<<<1, 256, 0, stream>>>(chunkCounts, nChunks, chunkOffsets);
    dest_kernel<<<nChunks, 256, 0, stream>>>(cs, NC, chunkOffsets, dest);

    if (fastPath) {
        int nPart = (P + CHUNK - 1) / CHUNK;
        partition_kernel<<<nPart, PBDIM, 0, stream>>>(dirs, pci, nsi, dest, gCursor, gBucket,
                                                      P, nbk);
        accum_kernel<<<nbk, 256, 0, stream>>>(gCursor, gBucket, out, NC);
    } else {
        zero_f32<<<2048, 256, 0, stream>>>(out, out_size);
        pair_kernel<<<(P + 255) / 256, 256, 0, stream>>>(dirs, pci, nsi, dest, out, P);
    }
}

// Round 9
// 67.946 us; speedup vs baseline: 9.1463x; 1.1323x over previous
//
#include <hip/hip_runtime.h>
#include <hip/hip_bf16.h>

#define NSPEC 4
#define NFEAT 144
#define RCUT 5.0f
#define RPB 64                 // centers per bucket / accum block
#define MAXB 1568              // max buckets (NC <= 100352)
#define CAP 1536               // pairs capacity per bucket (avg ~1150)
#define CHUNK 8192             // pairs per partition block
#define PBDIM 1024             // partition block threads (16 waves)
#define IPT (CHUNK / PBDIM)    // items per thread = 8
#define ASTRIDE 148            // stage stride (floats): 16B-aligned rows, 2-way banks max

// ---------- utility ----------

__global__ void zero_f32(float* __restrict__ out, int n) {
    int n4 = n >> 2;
    float4* o4 = (float4*)out;
    for (int i = blockIdx.x * blockDim.x + threadIdx.x; i < n4; i += gridDim.x * blockDim.x)
        o4[i] = make_float4(0.f, 0.f, 0.f, 0.f);
    int tail = n & 3;
    if (blockIdx.x == 0 && threadIdx.x < tail) out[n4 * 4 + threadIdx.x] = 0.f;
}

// ---------- stable counting-sort rank of centers by species (+ cursor zeroing) ----------

__global__ void count_kernel(const int* __restrict__ cs, int n, int* __restrict__ chunkCounts,
                             int* __restrict__ zeroPtr, int zeroN) {
    __shared__ int cnt[NSPEC];
    if (threadIdx.x < NSPEC) cnt[threadIdx.x] = 0;
    __syncthreads();
    int i = blockIdx.x * blockDim.x + threadIdx.x;
    if (i < n) atomicAdd(&cnt[cs[i]], 1);
    if (zeroPtr) {
        for (int j = i; j < zeroN; j += gridDim.x * blockDim.x) zeroPtr[j] = 0;
    }
    __syncthreads();
    if (threadIdx.x < NSPEC) chunkCounts[blockIdx.x * NSPEC + threadIdx.x] = cnt[threadIdx.x];
}

__global__ void scanP_kernel(const int* __restrict__ chunkCounts, int nChunks,
                             int* __restrict__ chunkOffsets) {
    __shared__ int totals[NSPEC];
    __shared__ int base4[NSPEC];
    int w = threadIdx.x >> 6;     // species
    int lane = threadIdx.x & 63;
    int carry = 0;
    for (int base = 0; base < nChunks; base += 64) {
        int c = base + lane;
        int v = (c < nChunks) ? chunkCounts[c * NSPEC + w] : 0;
        int incl = v;
        #pragma unroll
        for (int off = 1; off < 64; off <<= 1) {
            int t = __shfl_up(incl, off);
            if (lane >= off) incl += t;
        }
        if (c < nChunks) chunkOffsets[c * NSPEC + w] = carry + incl - v;
        carry += __shfl(incl, 63);
    }
    if (lane == 0) totals[w] = carry;
    __syncthreads();
    if (threadIdx.x == 0) {
        int b = 0;
        for (int s = 0; s < NSPEC; ++s) { base4[s] = b; b += totals[s]; }
    }
    __syncthreads();
    for (int i = threadIdx.x; i < nChunks * NSPEC; i += blockDim.x)
        chunkOffsets[i] += base4[i & (NSPEC - 1)];
}

__global__ void dest_kernel(const int* __restrict__ cs, int n,
                            const int* __restrict__ chunkOffsets, int* __restrict__ dest) {
    __shared__ int waveCnt[4][NSPEC];
    int chunk = blockIdx.x;
    int i = chunk * blockDim.x + threadIdx.x;
    int s = (i < n) ? cs[i] : -1;
    int lane = threadIdx.x & 63;
    int wave = threadIdx.x >> 6;

    int lanePrefix = 0;
    for (int sp = 0; sp < NSPEC; ++sp) {
        unsigned long long b = __ballot(s == sp);
        if (lane == 0) waveCnt[wave][sp] = __popcll(b);
        if (sp == s) lanePrefix = __popcll(b & ((1ull << lane) - 1ull));
    }
    __syncthreads();
    if (i < n) {
        int wp = 0;
        for (int w = 0; w < wave; ++w) wp += waveCnt[w][s];
        dest[i] = chunkOffsets[chunk * NSPEC + s] + wp + lanePrefix;
    }
}

// ---------- partition: LDS counting-sort of 8192 pairs into center-block buckets ----------
// payload u: bits[31:8] = r (low 8 mantissa bits replaced), bits[7:2] = center&63,
// bits[1:0] = species. No dest gather here — permutation applied at accum write-out.

__global__ void __launch_bounds__(PBDIM) partition_kernel(
        const float* __restrict__ dirs, const int* __restrict__ pci,
        const int* __restrict__ nsi,
        int* __restrict__ gCursor, unsigned* __restrict__ gBucket, int P, int nbk) {
    __shared__ unsigned sSort[CHUNK];
    __shared__ int sHist[MAXB];
    __shared__ int sOffs[MAXB];
    __shared__ int sWaveTot[PBDIM / 64];

    int tid = threadIdx.x;
    int base = blockIdx.x * CHUNK;

    for (int i = tid; i < nbk; i += PBDIM) sHist[i] = 0;
    __syncthreads();

    unsigned uu[IPT];
    int bb[IPT];
    #pragma unroll
    for (int j = 0; j < IPT; ++j) {
        int i = base + j * PBDIM + tid;
        int bkt = -1; unsigned u = 0;
        if (i < P) {
            float x = dirs[3 * i + 0], y = dirs[3 * i + 1], z = dirs[3 * i + 2];
            float r2 = x * x + y * y + z * z;
            if (r2 < RCUT * RCUT) {
                float r = sqrtf(r2);
                int c = pci[i];
                bkt = c >> 6;
                u = (__float_as_uint(r) & 0xFFFFFF00u) | ((unsigned)(c & 63) << 2) |
                    (unsigned)nsi[i];
                atomicAdd(&sHist[bkt], 1);
            }
        }
        uu[j] = u; bb[j] = bkt;
    }
    __syncthreads();

    // block exclusive scan of sHist[0..nbk) into sOffs
    int seg = (nbk + PBDIM - 1) / PBDIM;
    int s0 = tid * seg;
    int run = 0;
    for (int k = 0; k < seg; ++k) {
        int idx = s0 + k;
        if (idx < nbk) { sOffs[idx] = run; run += sHist[idx]; }
    }
    int lane = tid & 63, wv = tid >> 6;
    int incl = run;
    #pragma unroll
    for (int off = 1; off < 64; off <<= 1) {
        int t = __shfl_up(incl, off);
        if (lane >= off) incl += t;
    }
    if (lane == 63) sWaveTot[wv] = incl;
    __syncthreads();
    int wbase = 0;
    for (int w = 0; w < wv; ++w) wbase += sWaveTot[w];
    int exc = wbase + incl - run;
    for (int k = 0; k < seg; ++k) {
        int idx = s0 + k;
        if (idx < nbk) sOffs[idx] += exc;
    }
    __syncthreads();

    // scatter into LDS sorted order (sOffs becomes end-cursor per bucket)
    #pragma unroll
    for (int j = 0; j < IPT; ++j) {
        if (bb[j] >= 0) {
            int pos = atomicAdd(&sOffs[bb[j]], 1);
            sSort[pos] = uu[j];
        }
    }
    __syncthreads();

    // flush each bucket's contiguous run to its global region
    for (int b = tid; b < nbk; b += PBDIM) {
        int c = sHist[b];
        if (!c) continue;
        int start = sOffs[b] - c;
        int g = atomicAdd(&gCursor[b], c);
        int lim = min(c, CAP - g);          // safety clamp, never expected to trigger
        unsigned* dst = gBucket + (size_t)b * CAP + g;
        for (int k = 0; k < lim; ++k) dst[k] = sSort[start + k];
    }
}

// ---------- accumulate: bucket -> LDS sort -> one thread per (center,species) bin ----------

__global__ void __launch_bounds__(256) accum_kernel(
        const int* __restrict__ gCursor, const unsigned* __restrict__ gBucket,
        const int* __restrict__ dest, float* __restrict__ out, int NC) {
    __shared__ unsigned sSort[CAP];
    __shared__ int sHist[256];
    __shared__ int sOff[256];
    __shared__ int sWaveTot[4];
    __shared__ int destLds[RPB];
    __shared__ float sStage[RPB * ASTRIDE];

    int tid = threadIdx.x;
    int b = blockIdx.x;
    int cBase = b * RPB;
    int n = min(gCursor[b], CAP);
    const unsigned* src = gBucket + (size_t)b * CAP;

    sHist[tid] = 0;
    if (tid < RPB && cBase + tid < NC) destLds[tid] = dest[cBase + tid];
    __syncthreads();

    // pass 1: histogram (bucket is tiny; second read below hits L2)
    for (int i = tid; i < n; i += 256) atomicAdd(&sHist[src[i] & 255u], 1);
    __syncthreads();

    // exclusive scan of 256 bins
    int lane = tid & 63, wv = tid >> 6;
    int v = sHist[tid];
    int incl = v;
    #pragma unroll
    for (int off = 1; off < 64; off <<= 1) {
        int t = __shfl_up(incl, off);
        if (lane >= off) incl += t;
    }
    if (lane == 63) sWaveTot[wv] = incl;
    __syncthreads();
    int wbase = 0;
    for (int w = 0; w < wv; ++w) wbase += sWaveTot[w];
    sOff[tid] = wbase + incl - v;
    __syncthreads();

    // pass 2: scatter into LDS sorted order (sOff becomes end-cursor)
    for (int i = tid; i < n; i += 256) {
        unsigned u = src[i];
        int pos = atomicAdd(&sOff[u & 255u], 1);
        sSort[pos] = u;
    }
    __syncthreads();

    // my bin = tid = (centerLocal<<2)|species
    int end = sOff[tid], start = end - sHist[tid];
    float acc[36];
    #pragma unroll
    for (int j = 0; j < 36; ++j) acc[j] = 0.f;

    for (int p = start; p < end; ++p) {
        unsigned u = sSort[p];
        float r = __uint_as_float(u & 0xFFFFFF00u);
        float r2 = r * r;
        float fc = 0.5f * (__cosf(0.6283185307179586f * r) + 1.0f);  // cos(pi*r/RCUT)
        float q = __expf(-r2 * 0.04f);                                // exp(-r^2/25)
        float q2 = q * q;
        float bq[12];  // bq[n] = q^(n+1), two independent x q^2 chains
        bq[0] = q; bq[1] = q2;
        #pragma unroll
        for (int nn = 2; nn < 12; ++nn) bq[nn] = bq[nn - 2] * q2;
        float a0 = fc, a1 = fc * r, a2 = a1 * r, a3 = a2 * r;
        #pragma unroll
        for (int nn = 0; nn < 12; ++nn) acc[nn]      = fmaf(a0, bq[nn], acc[nn]);
        #pragma unroll
        for (int nn = 0; nn < 10; ++nn) acc[12 + nn] = fmaf(a1, bq[nn], acc[12 + nn]);
        #pragma unroll
        for (int nn = 0; nn < 8; ++nn)  acc[22 + nn] = fmaf(a2, bq[nn], acc[22 + nn]);
        #pragma unroll
        for (int nn = 0; nn < 6; ++nn)  acc[30 + nn] = fmaf(a3, bq[nn], acc[30 + nn]);
    }

    // stage in [row][col] layout: row = tid>>2, col = off_l + 4n + (tid&3)
    {
        float* rowp = sStage + (tid >> 2) * ASTRIDE + (tid & 3);
        #pragma unroll
        for (int nn = 0; nn < 12; ++nn) rowp[nn * 4]       = acc[nn];
        #pragma unroll
        for (int nn = 0; nn < 10; ++nn) rowp[48 + nn * 4]  = acc[12 + nn];
        #pragma unroll
        for (int nn = 0; nn < 8; ++nn)  rowp[88 + nn * 4]  = acc[22 + nn];
        #pragma unroll
        for (int nn = 0; nn < 6; ++nn)  rowp[120 + nn * 4] = acc[30 + nn];
    }
    __syncthreads();

    // write out: 36 float4 per row, row -> out[dest[center]]
    int nRows = min(RPB, NC - cBase);
    int lim = nRows * 36;
    for (int i = tid; i < lim; i += 256) {
        int row = i / 36;
        int c4 = i - row * 36;
        float4 val = *(const float4*)(sStage + row * ASTRIDE + c4 * 4);
        *(float4*)(out + (size_t)destLds[row] * NFEAT + c4 * 4) = val;
    }
}

// ---------- fallback: direct atomic scatter ----------

__global__ void pair_kernel(const float* __restrict__ dirs,
                            const int* __restrict__ pci,
                            const int* __restrict__ nsi,
                            const int* __restrict__ dest,
                            float* __restrict__ out, int P) {
    int i = blockIdx.x * blockDim.x + threadIdx.x;
    if (i >= P) return;
    float x = dirs[3 * i + 0], y = dirs[3 * i + 1], z = dirs[3 * i + 2];
    float r2 = x * x + y * y + z * z;
    float r = sqrtf(r2);
    if (r >= RCUT) return;
    float fc = 0.5f * (cosf(3.14159265358979323846f * r * (1.0f / RCUT)) + 1.0f);
    float q = expf(-r2 * (1.0f / (RCUT * RCUT)));
    int rowb = dest[pci[i]] * NFEAT;
    int s = nsi[i];
    float* o = out + rowb + s;
    float rl = fc;
    const int nmax[4] = {12, 10, 8, 6};
    const int offl[4] = {0, 48, 88, 120};
    #pragma unroll
    for (int l = 0; l < 4; ++l) {
        float e = q;
        for (int n = 0; n < nmax[l]; ++n) { atomicAdd(o + offl[l] + n * NSPEC, rl * e); e *= q; }
        rl *= r;
    }
}

extern "C" void kernel_launch(void* const* d_in, const int* in_sizes, int n_in,
                              void* d_out, int out_size, void* d_ws, size_t ws_size,
                              hipStream_t stream) {
    const float* dirs = (const float*)d_in[0];
    const int* pci = (const int*)d_in[1];
    const int* nsi = (const int*)d_in[2];
    const int* cs = (const int*)d_in[3];
    int P = in_sizes[1];
    int NC = in_sizes[3];
    float* out = (float*)d_out;

    int nChunks = (NC + 255) / 256;
    int nbk = (NC + RPB - 1) / RPB;

    // ws layout (ints)
    int* chunkCounts  = (int*)d_ws;                      // nChunks*4
    int* chunkOffsets = chunkCounts + nChunks * NSPEC;   // nChunks*4
    int* dest         = chunkOffsets + nChunks * NSPEC;  // NC
    int* gCursor      = dest + NC;                       // nbk
    unsigned* gBucket = (unsigned*)(gCursor + nbk);      // nbk*CAP

    size_t need = ((size_t)(2 * nChunks * NSPEC) + (size_t)NC + (size_t)nbk +
                   (size_t)nbk * CAP) * sizeof(int);
    bool fastPath = (ws_size >= need) && (nbk <= MAXB);

    // center -> sorted-row map (count also zeroes gCursor on the fast path)
    count_kernel<<<nChunks, 256, 0, stream>>>(cs, NC, chunkCounts,
                                              fastPath ? gCursor : (int*)nullptr, nbk);
    scanP_kernel<<<1, 256, 0, stream>>>(chunkCounts, nChunks, chunkOffsets);
    dest_kernel<<<nChunks, 256, 0, stream>>>(cs, NC, chunkOffsets, dest);

    if (fastPath) {
        int nPart = (P + CHUNK - 1) / CHUNK;
        partition_kernel<<<nPart, PBDIM, 0, stream>>>(dirs, pci, nsi, gCursor, gBucket, P, nbk);
        accum_kernel<<<nbk, 256, 0, stream>>>(gCursor, gBucket, dest, out, NC);
    } else {
        zero_f32<<<2048, 256, 0, stream>>>(out, out_size);
        pair_kernel<<<(P + 255) / 256, 256, 0, stream>>>(dirs, pci, nsi, dest, out, P);
    }
}

// Round 10
// 59.093 us; speedup vs baseline: 10.5164x; 1.1498x over previous
//
#include <hip/hip_runtime.h>
#include <hip/hip_bf16.h>

#define NSPEC 4
#define NFEAT 144
#define RCUT 5.0f
#define RPB 64                 // centers per bucket / accum block
#define MAXB 1568              // max buckets (NC <= 100352)
#define CAP 1536               // pairs capacity per bucket (avg ~1178, +10 sigma)
#define CHUNK 8192             // pairs per partition block
#define PBDIM 1024             // partdest block threads (16 waves)
#define IPT (CHUNK / PBDIM)    // items per thread = 8
#define ASTRIDE 148            // accum stage stride (floats)
#define LDSN (CHUNK + 2 * MAXB + 16 + 64)

// ---------- utility ----------

__global__ void zero_f32(float* __restrict__ out, int n) {
    int n4 = n >> 2;
    float4* o4 = (float4*)out;
    for (int i = blockIdx.x * blockDim.x + threadIdx.x; i < n4; i += gridDim.x * blockDim.x)
        o4[i] = make_float4(0.f, 0.f, 0.f, 0.f);
    int tail = n & 3;
    if (blockIdx.x == 0 && threadIdx.x < tail) out[n4 * 4 + threadIdx.x] = 0.f;
}

// ---------- prep: per-chunk species counts + gCursor zeroing ----------

__global__ void prep_kernel(const int* __restrict__ cs, int n, int* __restrict__ chunkCounts,
                            int* __restrict__ zeroPtr, int zeroN) {
    __shared__ int cnt[NSPEC];
    if (threadIdx.x < NSPEC) cnt[threadIdx.x] = 0;
    __syncthreads();
    int i = blockIdx.x * blockDim.x + threadIdx.x;
    if (i < n) atomicAdd(&cnt[cs[i]], 1);
    if (zeroPtr) {
        for (int j = i; j < zeroN; j += gridDim.x * blockDim.x) zeroPtr[j] = 0;
    }
    __syncthreads();
    if (threadIdx.x < NSPEC) chunkCounts[blockIdx.x * NSPEC + threadIdx.x] = cnt[threadIdx.x];
}

// ---------- fused partition + dest kernel ----------
// blocks [0, nPart):      partition pairs into center-block buckets
// blocks [nPart, +nChunks): compute dest[] for one 256-center chunk (redundant reduce)
// payload u: bits[31:8] = r (low 8 mantissa bits replaced), bits[7:2] = center&63,
// bits[1:0] = species.

__global__ void __launch_bounds__(PBDIM) partdest_kernel(
        const float* __restrict__ dirs, const int* __restrict__ pci,
        const int* __restrict__ nsi, const int* __restrict__ cs,
        const int* __restrict__ chunkCounts, int* __restrict__ dest,
        int* __restrict__ gCursor, unsigned* __restrict__ gBucket,
        int P, int NC, int nbk, int nChunks, int nPart) {
    __shared__ int ldsraw[LDSN];

    int tid = threadIdx.x;

    if ((int)blockIdx.x < nPart) {
        // ---------------- partition job ----------------
        unsigned* sSort = (unsigned*)ldsraw;          // CHUNK
        int* sHist = ldsraw + CHUNK;                  // MAXB
        int* sOffs = sHist + MAXB;                    // MAXB
        int* sWaveTot = sOffs + MAXB;                 // 16

        int base = blockIdx.x * CHUNK;

        for (int i = tid; i < nbk; i += PBDIM) sHist[i] = 0;
        __syncthreads();

        unsigned uu[IPT];
        int bb[IPT];
        #pragma unroll
        for (int j = 0; j < IPT; ++j) {
            int i = base + j * PBDIM + tid;
            int bkt = -1; unsigned u = 0;
            if (i < P) {
                float x = dirs[3 * i + 0], y = dirs[3 * i + 1], z = dirs[3 * i + 2];
                float r2 = x * x + y * y + z * z;
                if (r2 < RCUT * RCUT) {
                    float r = sqrtf(r2);
                    int c = pci[i];
                    bkt = c >> 6;
                    u = (__float_as_uint(r) & 0xFFFFFF00u) | ((unsigned)(c & 63) << 2) |
                        (unsigned)nsi[i];
                    atomicAdd(&sHist[bkt], 1);
                }
            }
            uu[j] = u; bb[j] = bkt;
        }
        __syncthreads();

        // block exclusive scan of sHist[0..nbk) into sOffs
        int seg = (nbk + PBDIM - 1) / PBDIM;
        int s0 = tid * seg;
        int run = 0;
        for (int k = 0; k < seg; ++k) {
            int idx = s0 + k;
            if (idx < nbk) { sOffs[idx] = run; run += sHist[idx]; }
        }
        int lane = tid & 63, wv = tid >> 6;
        int incl = run;
        #pragma unroll
        for (int off = 1; off < 64; off <<= 1) {
            int t = __shfl_up(incl, off);
            if (lane >= off) incl += t;
        }
        if (lane == 63) sWaveTot[wv] = incl;
        __syncthreads();
        int wbase = 0;
        for (int w = 0; w < wv; ++w) wbase += sWaveTot[w];
        int exc = wbase + incl - run;
        for (int k = 0; k < seg; ++k) {
            int idx = s0 + k;
            if (idx < nbk) sOffs[idx] += exc;
        }
        __syncthreads();

        // scatter into LDS sorted order (sOffs becomes end-cursor per bucket)
        #pragma unroll
        for (int j = 0; j < IPT; ++j) {
            if (bb[j] >= 0) {
                int pos = atomicAdd(&sOffs[bb[j]], 1);
                sSort[pos] = uu[j];
            }
        }
        __syncthreads();

        // flush each bucket's contiguous run to its global region
        for (int b = tid; b < nbk; b += PBDIM) {
            int c = sHist[b];
            if (!c) continue;
            int start = sOffs[b] - c;
            int g = atomicAdd(&gCursor[b], c);
            int lim = min(c, CAP - g);      // safety clamp
            unsigned* dst = gBucket + (size_t)b * CAP + g;
            for (int k = 0; k < lim; ++k) dst[k] = sSort[start + k];
        }
    } else {
        // ---------------- dest job: chunk cj ----------------
        int cj = blockIdx.x - nPart;
        if (cj >= nChunks) return;
        int* red   = ldsraw;        // 8: pref[4], tot[4]
        int* cOffs = ldsraw + 8;    // 4
        int* wCnt  = ldsraw + 12;   // 16*4

        if (tid < 8) red[tid] = 0;
        __syncthreads();

        int nCE = nChunks * NSPEC;
        for (int idx = tid; idx < nCE; idx += PBDIM) {
            int c = idx >> 2, s = idx & 3;
            int v = chunkCounts[idx];
            if (v) {
                if (c < cj) atomicAdd(&red[s], v);
                atomicAdd(&red[4 + s], v);
            }
        }
        __syncthreads();

        if (tid == 0) {
            int b = 0;
            #pragma unroll
            for (int s = 0; s < NSPEC; ++s) { cOffs[s] = b + red[s]; b += red[4 + s]; }
        }
        __syncthreads();

        // ballot rank for the 256 centers of this chunk (threads 0-255 active)
        int i = cj * 256 + tid;
        int s = (tid < 256 && i < NC) ? cs[i] : -1;
        int lane = tid & 63, wv = tid >> 6;
        int lanePrefix = 0;
        #pragma unroll
        for (int sp = 0; sp < NSPEC; ++sp) {
            unsigned long long b = __ballot(s == sp);
            if (lane == 0) wCnt[wv * 4 + sp] = __popcll(b);
            if (sp == s) lanePrefix = __popcll(b & ((1ull << lane) - 1ull));
        }
        __syncthreads();
        if (s >= 0) {
            int wp = 0;
            for (int w = 0; w < wv; ++w) wp += wCnt[w * 4 + s];
            dest[i] = cOffs[s] + wp + lanePrefix;
        }
    }
}

// ---------- accumulate: bucket -> LDS sort -> one thread per (center,species) bin ----------

__global__ void __launch_bounds__(256) accum_kernel(
        const int* __restrict__ gCursor, const unsigned* __restrict__ gBucket,
        const int* __restrict__ dest, float* __restrict__ out, int NC) {
    __shared__ unsigned sSort[CAP];
    __shared__ int sHist[256];
    __shared__ int sOff[256];
    __shared__ int sWaveTot[4];
    __shared__ int destLds[RPB];
    __shared__ float sStage[RPB * ASTRIDE];

    int tid = threadIdx.x;
    int b = blockIdx.x;
    int cBase = b * RPB;
    int n = min(gCursor[b], CAP);
    const unsigned* src = gBucket + (size_t)b * CAP;

    sHist[tid] = 0;
    if (tid < RPB && cBase + tid < NC) destLds[tid] = dest[cBase + tid];
    __syncthreads();

    // pass 1: histogram (bucket tiny; second read below hits L2)
    for (int i = tid; i < n; i += 256) atomicAdd(&sHist[src[i] & 255u], 1);
    __syncthreads();

    // exclusive scan of 256 bins
    int lane = tid & 63, wv = tid >> 6;
    int v = sHist[tid];
    int incl = v;
    #pragma unroll
    for (int off = 1; off < 64; off <<= 1) {
        int t = __shfl_up(incl, off);
        if (lane >= off) incl += t;
    }
    if (lane == 63) sWaveTot[wv] = incl;
    __syncthreads();
    int wbase = 0;
    for (int w = 0; w < wv; ++w) wbase += sWaveTot[w];
    sOff[tid] = wbase + incl - v;
    __syncthreads();

    // pass 2: scatter into LDS sorted order (sOff becomes end-cursor)
    for (int i = tid; i < n; i += 256) {
        unsigned u = src[i];
        int pos = atomicAdd(&sOff[u & 255u], 1);
        sSort[pos] = u;
    }
    __syncthreads();

    // my bin = tid = (centerLocal<<2)|species
    int end = sOff[tid], start = end - sHist[tid];
    float acc[36];
    #pragma unroll
    for (int j = 0; j < 36; ++j) acc[j] = 0.f;

    for (int p = start; p < end; ++p) {
        unsigned u = sSort[p];
        float r = __uint_as_float(u & 0xFFFFFF00u);
        float r2 = r * r;
        float fc = 0.5f * (__cosf(0.6283185307179586f * r) + 1.0f);  // cos(pi*r/RCUT)
        float q = __expf(-r2 * 0.04f);                                // exp(-r^2/25)
        float q2 = q * q;
        float bq[12];  // bq[n] = q^(n+1), two independent x q^2 chains
        bq[0] = q; bq[1] = q2;
        #pragma unroll
        for (int nn = 2; nn < 12; ++nn) bq[nn] = bq[nn - 2] * q2;
        float a0 = fc, a1 = fc * r, a2 = a1 * r, a3 = a2 * r;
        #pragma unroll
        for (int nn = 0; nn < 12; ++nn) acc[nn]      = fmaf(a0, bq[nn], acc[nn]);
        #pragma unroll
        for (int nn = 0; nn < 10; ++nn) acc[12 + nn] = fmaf(a1, bq[nn], acc[12 + nn]);
        #pragma unroll
        for (int nn = 0; nn < 8; ++nn)  acc[22 + nn] = fmaf(a2, bq[nn], acc[22 + nn]);
        #pragma unroll
        for (int nn = 0; nn < 6; ++nn)  acc[30 + nn] = fmaf(a3, bq[nn], acc[30 + nn]);
    }

    // stage in [row][col] layout: row = tid>>2, col = off_l + 4n + (tid&3)
    {
        float* rowp = sStage + (tid >> 2) * ASTRIDE + (tid & 3);
        #pragma unroll
        for (int nn = 0; nn < 12; ++nn) rowp[nn * 4]       = acc[nn];
        #pragma unroll
        for (int nn = 0; nn < 10; ++nn) rowp[48 + nn * 4]  = acc[12 + nn];
        #pragma unroll
        for (int nn = 0; nn < 8; ++nn)  rowp[88 + nn * 4]  = acc[22 + nn];
        #pragma unroll
        for (int nn = 0; nn < 6; ++nn)  rowp[120 + nn * 4] = acc[30 + nn];
    }
    __syncthreads();

    // write out: 36 float4 per row, row -> out[dest[center]]
    int nRows = min(RPB, NC - cBase);
    int lim = nRows * 36;
    for (int i = tid; i < lim; i += 256) {
        int row = i / 36;
        int c4 = i - row * 36;
        float4 val = *(const float4*)(sStage + row * ASTRIDE + c4 * 4);
        *(float4*)(out + (size_t)destLds[row] * NFEAT + c4 * 4) = val;
    }
}

// ---------- fallback: direct atomic scatter ----------

__global__ void pair_kernel(const float* __restrict__ dirs,
                            const int* __restrict__ pci,
                            const int* __restrict__ nsi,
                            const int* __restrict__ dest,
                            float* __restrict__ out, int P) {
    int i = blockIdx.x * blockDim.x + threadIdx.x;
    if (i >= P) return;
    float x = dirs[3 * i + 0], y = dirs[3 * i + 1], z = dirs[3 * i + 2];
    float r2 = x * x + y * y + z * z;
    float r = sqrtf(r2);
    if (r >= RCUT) return;
    float fc = 0.5f * (cosf(3.14159265358979323846f * r * (1.0f / RCUT)) + 1.0f);
    float q = expf(-r2 * (1.0f / (RCUT * RCUT)));
    int rowb = dest[pci[i]] * NFEAT;
    int s = nsi[i];
    float* o = out + rowb + s;
    float rl = fc;
    const int nmax[4] = {12, 10, 8, 6};
    const int offl[4] = {0, 48, 88, 120};
    #pragma unroll
    for (int l = 0; l < 4; ++l) {
        float e = q;
        for (int n = 0; n < nmax[l]; ++n) { atomicAdd(o + offl[l] + n * NSPEC, rl * e); e *= q; }
        rl *= r;
    }
}

extern "C" void kernel_launch(void* const* d_in, const int* in_sizes, int n_in,
                              void* d_out, int out_size, void* d_ws, size_t ws_size,
                              hipStream_t stream) {
    const float* dirs = (const float*)d_in[0];
    const int* pci = (const int*)d_in[1];
    const int* nsi = (const int*)d_in[2];
    const int* cs = (const int*)d_in[3];
    int P = in_sizes[1];
    int NC = in_sizes[3];
    float* out = (float*)d_out;

    int nChunks = (NC + 255) / 256;
    int nbk = (NC + RPB - 1) / RPB;
    int nPart = (P + CHUNK - 1) / CHUNK;

    // ws layout (ints)
    int* chunkCounts  = (int*)d_ws;                      // nChunks*4
    int* dest         = chunkCounts + nChunks * NSPEC;   // NC
    int* gCursor      = dest + NC;                       // nbk
    unsigned* gBucket = (unsigned*)(gCursor + nbk);      // nbk*CAP

    size_t need = ((size_t)(nChunks * NSPEC) + (size_t)NC + (size_t)nbk +
                   (size_t)nbk * CAP) * sizeof(int);
    bool fastPath = (ws_size >= need) && (nbk <= MAXB);

    if (fastPath) {
        prep_kernel<<<nChunks, 256, 0, stream>>>(cs, NC, chunkCounts, gCursor, nbk);
        partdest_kernel<<<nPart + nChunks, PBDIM, 0, stream>>>(
            dirs, pci, nsi, cs, chunkCounts, dest, gCursor, gBucket,
            P, NC, nbk, nChunks, nPart);
        accum_kernel<<<nbk, 256, 0, stream>>>(gCursor, gBucket, dest, out, NC);
    } else {
        // fallback: prep + dest-only partdest + atomic pair scatter
        prep_kernel<<<nChunks, 256, 0, stream>>>(cs, NC, chunkCounts, (int*)nullptr, 0);
        partdest_kernel<<<nChunks, PBDIM, 0, stream>>>(
            dirs, pci, nsi, cs, chunkCounts, dest, (int*)d_ws /*unused*/, (unsigned*)d_ws,
            0 /*P=0 -> no partition blocks*/, NC, nbk, nChunks, 0);
        zero_f32<<<2048, 256, 0, stream>>>(out, out_size);
        pair_kernel<<<(P + 255) / 256, 256, 0, stream>>>(dirs, pci, nsi, dest, out, P);
    }
}